// Round 2
// baseline (8008.051 us; speedup 1.0000x reference)
//
#include <hip/hip_runtime.h>
#include <hip/hip_bf16.h>

typedef __hip_bfloat16 bf16;

#define NT 50000
#define NP 50000
#define NE 200000
#define HH 8
#define DD 32
#define CC 256   // H*D

__device__ __forceinline__ float bu2f(unsigned short u) {
  return __uint_as_float(((unsigned)u) << 16);
}
__device__ __forceinline__ unsigned enc_f(float x) {
  unsigned u = __float_as_uint(x);
  return (u & 0x80000000u) ? ~u : (u | 0x80000000u);
}
__device__ __forceinline__ float dec_f(unsigned u) {
  unsigned b = (u & 0x80000000u) ? (u ^ 0x80000000u) : ~u;
  return __uint_as_float(b);
}

// -------- zero fill (replaces hipMemsetAsync; graph-capture safe) --------
__global__ __launch_bounds__(256) void zero_f4(float4* __restrict__ p, int n4) {
  int i = blockIdx.x * 256 + threadIdx.x;
  if (i < n4) p[i] = make_float4(0.f, 0.f, 0.f, 0.f);
}

// -------- f32 -> bf16 convert (input x -> node state) --------
__global__ __launch_bounds__(256) void cvt_f2b(const float* __restrict__ in,
                                               bf16* __restrict__ out, int n) {
  int i = blockIdx.x * 256 + threadIdx.x;
  if (i < n) out[i] = __float2bfloat16(in[i]);
}

// -------- GEMM: C[m,n] = sum_k A[m,k]*W[k,n] + bias[n]; N=256 fixed --------
// A bf16 (M x K), W f32 (K x 256), bias f32 (256), out bf16 (M x 256), f32 accum
__global__ __launch_bounds__(256) void gemm_bias(
    const bf16* __restrict__ A, const float* __restrict__ W,
    const float* __restrict__ bias, bf16* __restrict__ Cout, int M, int K) {
  __shared__ float As[16][64];
  __shared__ float Ws[16][68];
  int bm = blockIdx.x, bn = blockIdx.y;
  int t = threadIdx.x;
  int tx = t & 15, ty = t >> 4;
  int row0 = bm * 64;
  float acc[4][4] = {};

  for (int k0 = 0; k0 < K; k0 += 16) {
    // A tile: 64 rows x 16 k; thread t loads 4 contiguous bf16 (8B)
    {
      int r = t >> 2;
      int kk = (t & 3) * 4;
      int row = row0 + r;
      ushort4 v = make_ushort4(0, 0, 0, 0);
      if (row < M)
        v = *(const ushort4*)((const unsigned short*)A + (size_t)row * K + k0 + kk);
      As[kk + 0][r] = bu2f(v.x); As[kk + 1][r] = bu2f(v.y);
      As[kk + 2][r] = bu2f(v.z); As[kk + 3][r] = bu2f(v.w);
    }
    // W tile: 16 k-rows x 64 cols (f32, coalesced)
    {
      int col = t & 63;
      int rr = t >> 6;  // 0..3
      #pragma unroll
      for (int i = 0; i < 4; i++) {
        int krow = i * 4 + rr;
        Ws[krow][col] = W[(size_t)(k0 + krow) * CC + bn * 64 + col];
      }
    }
    __syncthreads();
    #pragma unroll
    for (int kk = 0; kk < 16; kk++) {
      float a[4], w[4];
      #pragma unroll
      for (int i = 0; i < 4; i++) a[i] = As[kk][ty * 4 + i];
      #pragma unroll
      for (int j = 0; j < 4; j++) w[j] = Ws[kk][tx * 4 + j];
      #pragma unroll
      for (int i = 0; i < 4; i++)
        #pragma unroll
        for (int j = 0; j < 4; j++) acc[i][j] += a[i] * w[j];
    }
    __syncthreads();
  }
  #pragma unroll
  for (int i = 0; i < 4; i++) {
    int row = row0 + ty * 4 + i;
    if (row >= M) continue;
    #pragma unroll
    for (int j = 0; j < 4; j++) {
      int col = bn * 64 + tx * 4 + j;
      Cout[(size_t)row * CC + col] = __float2bfloat16(acc[i][j] + bias[col]);
    }
  }
}

// -------- edge logits + segment max --------
// wave per edge: lane -> h = lane>>3, sub = lane&7, 4 contiguous d-elements each
__global__ __launch_bounds__(256) void edge_logits(
    const int* __restrict__ src, const int* __restrict__ dst,
    const bf16* __restrict__ fs, const bf16* __restrict__ fd,
    const float* __restrict__ attn, float* __restrict__ logits,
    unsigned* __restrict__ mx) {
  int wave = (blockIdx.x * 256 + threadIdx.x) >> 6;
  if (wave >= NE) return;
  int lane = threadIdx.x & 63;
  int h = lane >> 3, sub = lane & 7;
  int s = src[wave], d = dst[wave];
  int off = h * DD + sub * 4;
  ushort4 us = *(const ushort4*)((const unsigned short*)fs + (size_t)s * CC + off);
  ushort4 ud = *(const ushort4*)((const unsigned short*)fd + (size_t)d * CC + off);
  float4 a4 = *(const float4*)(attn + off);
  float sum = 0.f;
  {
    float e0 = bu2f(us.x) + bu2f(ud.x); e0 = e0 > 0.f ? e0 : 0.2f * e0; sum += e0 * a4.x;
    float e1 = bu2f(us.y) + bu2f(ud.y); e1 = e1 > 0.f ? e1 : 0.2f * e1; sum += e1 * a4.y;
    float e2 = bu2f(us.z) + bu2f(ud.z); e2 = e2 > 0.f ? e2 : 0.2f * e2; sum += e2 * a4.z;
    float e3 = bu2f(us.w) + bu2f(ud.w); e3 = e3 > 0.f ? e3 : 0.2f * e3; sum += e3 * a4.w;
  }
  sum += __shfl_xor(sum, 1);
  sum += __shfl_xor(sum, 2);
  sum += __shfl_xor(sum, 4);
  if (sub == 0) {
    logits[(size_t)wave * HH + h] = sum;
    atomicMax(&mx[(size_t)d * HH + h], enc_f(sum));
  }
}

// -------- exp + denominator --------
__global__ __launch_bounds__(256) void edge_expden(
    const int* __restrict__ dst, float* __restrict__ logits,
    const unsigned* __restrict__ mx, float* __restrict__ den) {
  int idx = blockIdx.x * 256 + threadIdx.x;
  if (idx >= NE * HH) return;
  int e = idx >> 3, h = idx & 7;
  int d = dst[e];
  float m = dec_f(mx[(size_t)d * HH + h]);
  float ex = __expf(logits[idx] - m);
  logits[idx] = ex;
  atomicAdd(&den[(size_t)d * HH + h], ex);
}

// -------- attention-weighted scatter-add --------
__global__ __launch_bounds__(256) void edge_aggr(
    const int* __restrict__ src, const int* __restrict__ dst,
    const bf16* __restrict__ fs, const float* __restrict__ logits,
    const float* __restrict__ den, float* __restrict__ acc) {
  int wave = (blockIdx.x * 256 + threadIdx.x) >> 6;
  if (wave >= NE) return;
  int lane = threadIdx.x & 63;
  int h = lane >> 3, sub = lane & 7;
  int s = src[wave], d = dst[wave];
  float alpha = logits[(size_t)wave * HH + h] / den[(size_t)d * HH + h];
  int off = h * DD + sub * 4;
  ushort4 us = *(const ushort4*)((const unsigned short*)fs + (size_t)s * CC + off);
  float* p = acc + (size_t)d * CC + off;
  atomicAdd(p + 0, alpha * bu2f(us.x));
  atomicAdd(p + 1, alpha * bu2f(us.y));
  atomicAdd(p + 2, alpha * bu2f(us.z));
  atomicAdd(p + 3, alpha * bu2f(us.w));
}

// -------- scale + ReLU -> bf16 node state; optionally emit f32 to d_out --------
__global__ __launch_bounds__(256) void finalize_k(
    const float* __restrict__ acc, float scale, bf16* __restrict__ hcur,
    float* __restrict__ outf, int n) {
  int i = blockIdx.x * 256 + threadIdx.x;
  if (i >= n) return;
  float v = acc[i] * scale;
  v = v > 0.f ? v : 0.f;
  hcur[i] = __float2bfloat16(v);
  if (outf) outf[i] = v;
}

extern "C" void kernel_launch(void* const* d_in, const int* in_sizes, int n_in,
                              void* d_out, int out_size, void* d_ws, size_t ws_size,
                              hipStream_t stream) {
  const float* x_tile = (const float*)d_in[0];
  const float* x_poi  = (const float*)d_in[1];
  const int* src_road = (const int*)d_in[2];
  const int* dst_road = (const int*)d_in[3];
  const int* src_tb   = (const int*)d_in[4];
  const int* dst_tb   = (const int*)d_in[5];
  const int* src_ct   = (const int*)d_in[6];
  const int* dst_ct   = (const int*)d_in[7];
  const float* Wsrc[3] = {(const float*)d_in[8],  (const float*)d_in[13], (const float*)d_in[18]};
  const float* bsrc[3] = {(const float*)d_in[9],  (const float*)d_in[14], (const float*)d_in[19]};
  const float* Wdst[3] = {(const float*)d_in[10], (const float*)d_in[15], (const float*)d_in[20]};
  const float* bdst[3] = {(const float*)d_in[11], (const float*)d_in[16], (const float*)d_in[21]};
  const float* attn[3] = {(const float*)d_in[12], (const float*)d_in[17], (const float*)d_in[22]};

  // workspace layout (214.4 MB total):
  // tacc, pacc : 2 x 50000*256 f32  (102.4 MB)  [adjacent -> one zero-fill]
  // ht, hp     : 2 x 50000*256 bf16 (51.2 MB)
  // fs, fd     : 2 x 50000*256 bf16 (51.2 MB)
  // logits     : 200000*8 f32       (6.4 MB)
  // mx, den    : 2 x 50000*8 u32/f32 (3.2 MB)   [adjacent -> one zero-fill]
  float* tacc = (float*)d_ws;
  float* pacc = tacc + (size_t)NT * CC;
  bf16* ht    = (bf16*)(pacc + (size_t)NP * CC);
  bf16* hp    = ht + (size_t)NT * CC;
  bf16* fs    = hp + (size_t)NP * CC;
  bf16* fd    = fs + (size_t)NT * CC;
  float* logits = (float*)(fd + (size_t)NT * CC);
  unsigned* mx  = (unsigned*)(logits + (size_t)NE * HH);
  float* den    = (float*)(mx + (size_t)NT * HH);

  // convert f32 inputs to bf16 node states
  cvt_f2b<<<(NT * 128 + 255) / 256, 256, 0, stream>>>(x_tile, ht, NT * 128);
  cvt_f2b<<<(NP * 128 + 255) / 256, 256, 0, stream>>>(x_poi, hp, NP * 128);

  for (int l = 0; l < 3; l++) {
    int K = (l == 0) ? 128 : 256;
    // zero tacc+pacc (contiguous 2*NT*CC floats)
    {
      int n4 = (2 * NT * CC) / 4;
      zero_f4<<<(n4 + 255) / 256, 256, 0, stream>>>((float4*)tacc, n4);
    }

    struct Rel {
      const bf16* hs; const bf16* hd;
      const int* s; const int* d;
      float* acc; int n_src; int n_dst;
    };
    Rel rels[3] = {
      {ht, ht, src_road, dst_road, tacc, NT, NT},
      {hp, ht, src_tb,   dst_tb,   tacc, NP, NT},
      {ht, hp, src_ct,   dst_ct,   pacc, NT, NP},
    };

    for (int r = 0; r < 3; r++) {
      const float* Ws = Wsrc[l] + (size_t)r * K * CC;
      const float* bs = bsrc[l] + (size_t)r * CC;
      const float* Wd = Wdst[l] + (size_t)r * K * CC;
      const float* bd = bdst[l] + (size_t)r * CC;
      const float* at = attn[l] + (size_t)r * CC;

      dim3 gs((rels[r].n_src + 63) / 64, 4);
      gemm_bias<<<gs, 256, 0, stream>>>(rels[r].hs, Ws, bs, fs, rels[r].n_src, K);
      dim3 gd((rels[r].n_dst + 63) / 64, 4);
      gemm_bias<<<gd, 256, 0, stream>>>(rels[r].hd, Wd, bd, fd, rels[r].n_dst, K);

      // zero mx+den (contiguous 2*NT*HH words)
      {
        int n4 = (2 * NT * HH) / 4;
        zero_f4<<<(n4 + 255) / 256, 256, 0, stream>>>((float4*)mx, n4);
      }

      edge_logits<<<(NE * 64) / 256, 256, 0, stream>>>(rels[r].s, rels[r].d, fs, fd, at, logits, mx);
      edge_expden<<<(NE * HH) / 256, 256, 0, stream>>>(rels[r].d, logits, mx, den);
      edge_aggr<<<(NE * 64) / 256, 256, 0, stream>>>(rels[r].s, rels[r].d, fs, logits, den, rels[r].acc);
    }

    float st = (l == 1) ? 0.5f : 1.0f;
    float* outT = (l == 2) ? (float*)d_out : nullptr;
    float* outP = (l == 2) ? ((float*)d_out + (size_t)NT * CC) : nullptr;
    finalize_k<<<(NT * CC + 255) / 256, 256, 0, stream>>>(tacc, st, ht, outT, NT * CC);
    finalize_k<<<(NP * CC + 255) / 256, 256, 0, stream>>>(pacc, 1.0f, hp, outP, NP * CC);
  }
}

// Round 3
// 2731.377 us; speedup vs baseline: 2.9319x; 2.9319x over previous
//
#include <hip/hip_runtime.h>
#include <hip/hip_bf16.h>

typedef __hip_bfloat16 bf16;

#define NT 50000
#define NP 50000
#define NE 200000
#define HH 8
#define DD 32
#define CC 256   // H*D

__device__ __forceinline__ float bu2f(unsigned short u) {
  return __uint_as_float(((unsigned)u) << 16);
}

// -------- utility fills / converts --------
__global__ __launch_bounds__(256) void cvt_f2b(const float* __restrict__ in,
                                               bf16* __restrict__ out, int n) {
  int i = blockIdx.x * 256 + threadIdx.x;
  if (i < n) out[i] = __float2bfloat16(in[i]);
}

__global__ __launch_bounds__(256) void zero_i(int* __restrict__ p, int n) {
  int i = blockIdx.x * 256 + threadIdx.x;
  if (i < n) p[i] = 0;
}

__global__ __launch_bounds__(256) void copy_i(const int* __restrict__ a,
                                              int* __restrict__ b, int n) {
  int i = blockIdx.x * 256 + threadIdx.x;
  if (i < n) b[i] = a[i];
}

// -------- CSR build --------
__global__ __launch_bounds__(256) void hist_k(const int* __restrict__ dst,
                                              int* __restrict__ deg) {
  int e = blockIdx.x * 256 + threadIdx.x;
  if (e < NE) atomicAdd(&deg[dst[e]], 1);
}

// single-block exclusive scan, n up to ~64K
__global__ __launch_bounds__(1024) void scan_k(const int* __restrict__ deg,
                                               int* __restrict__ off, int n) {
  __shared__ int buf[1024];
  __shared__ int carry_s;
  int tid = threadIdx.x;
  if (tid == 0) carry_s = 0;
  __syncthreads();
  for (int base = 0; base < n; base += 1024) {
    int i = base + tid;
    int v = (i < n) ? deg[i] : 0;
    buf[tid] = v;
    __syncthreads();
    for (int s = 1; s < 1024; s <<= 1) {
      int t = (tid >= s) ? buf[tid - s] : 0;
      __syncthreads();
      buf[tid] += t;
      __syncthreads();
    }
    int carry = carry_s;
    if (i < n) off[i] = carry + buf[tid] - v;
    __syncthreads();
    if (tid == 1023) carry_s = carry + buf[1023];
    __syncthreads();
  }
  if (tid == 0) off[n] = carry_s;
}

__global__ __launch_bounds__(256) void fill_k(const int* __restrict__ dst,
                                              int* __restrict__ cursor,
                                              int* __restrict__ eids) {
  int e = blockIdx.x * 256 + threadIdx.x;
  if (e < NE) {
    int p = atomicAdd(&cursor[dst[e]], 1);
    eids[p] = e;
  }
}

// -------- GEMM: C[m,n] = sum_k A[m,k]*W[k,n] + bias[n]; N=256 fixed --------
// A bf16 (M x K), W f32 (K x 256), bias f32 (256), out bf16 (M x 256), f32 accum
__global__ __launch_bounds__(256) void gemm_bias(
    const bf16* __restrict__ A, const float* __restrict__ W,
    const float* __restrict__ bias, bf16* __restrict__ Cout, int M, int K) {
  __shared__ float As[16][64];
  __shared__ float Ws[16][68];
  int bm = blockIdx.x, bn = blockIdx.y;
  int t = threadIdx.x;
  int tx = t & 15, ty = t >> 4;
  int row0 = bm * 64;
  float acc[4][4] = {};

  for (int k0 = 0; k0 < K; k0 += 16) {
    {
      int r = t >> 2;
      int kk = (t & 3) * 4;
      int row = row0 + r;
      ushort4 v = make_ushort4(0, 0, 0, 0);
      if (row < M)
        v = *(const ushort4*)((const unsigned short*)A + (size_t)row * K + k0 + kk);
      As[kk + 0][r] = bu2f(v.x); As[kk + 1][r] = bu2f(v.y);
      As[kk + 2][r] = bu2f(v.z); As[kk + 3][r] = bu2f(v.w);
    }
    {
      int col = t & 63;
      int rr = t >> 6;
      #pragma unroll
      for (int i = 0; i < 4; i++) {
        int krow = i * 4 + rr;
        Ws[krow][col] = W[(size_t)(k0 + krow) * CC + bn * 64 + col];
      }
    }
    __syncthreads();
    #pragma unroll
    for (int kk = 0; kk < 16; kk++) {
      float a[4], w[4];
      #pragma unroll
      for (int i = 0; i < 4; i++) a[i] = As[kk][ty * 4 + i];
      #pragma unroll
      for (int j = 0; j < 4; j++) w[j] = Ws[kk][tx * 4 + j];
      #pragma unroll
      for (int i = 0; i < 4; i++)
        #pragma unroll
        for (int j = 0; j < 4; j++) acc[i][j] += a[i] * w[j];
    }
    __syncthreads();
  }
  #pragma unroll
  for (int i = 0; i < 4; i++) {
    int row = row0 + ty * 4 + i;
    if (row >= M) continue;
    #pragma unroll
    for (int j = 0; j < 4; j++) {
      int col = bn * 64 + tx * 4 + j;
      Cout[(size_t)row * CC + col] = __float2bfloat16(acc[i][j] + bias[col]);
    }
  }
}

// -------- edge logits (wave per edge; no atomics) --------
__global__ __launch_bounds__(256) void edge_logits(
    const int* __restrict__ src, const int* __restrict__ dst,
    const bf16* __restrict__ fs, const bf16* __restrict__ fd,
    const float* __restrict__ attn, float* __restrict__ logits) {
  int wave = (blockIdx.x * 256 + threadIdx.x) >> 6;
  if (wave >= NE) return;
  int lane = threadIdx.x & 63;
  int h = lane >> 3, sub = lane & 7;
  int s = src[wave], d = dst[wave];
  int off = h * DD + sub * 4;
  ushort4 us = *(const ushort4*)((const unsigned short*)fs + (size_t)s * CC + off);
  ushort4 ud = *(const ushort4*)((const unsigned short*)fd + (size_t)d * CC + off);
  float4 a4 = *(const float4*)(attn + off);
  float sum = 0.f;
  {
    float e0 = bu2f(us.x) + bu2f(ud.x); e0 = e0 > 0.f ? e0 : 0.2f * e0; sum += e0 * a4.x;
    float e1 = bu2f(us.y) + bu2f(ud.y); e1 = e1 > 0.f ? e1 : 0.2f * e1; sum += e1 * a4.y;
    float e2 = bu2f(us.z) + bu2f(ud.z); e2 = e2 > 0.f ? e2 : 0.2f * e2; sum += e2 * a4.z;
    float e3 = bu2f(us.w) + bu2f(ud.w); e3 = e3 > 0.f ? e3 : 0.2f * e3; sum += e3 * a4.w;
  }
  sum += __shfl_xor(sum, 1);
  sum += __shfl_xor(sum, 2);
  sum += __shfl_xor(sum, 4);
  if (sub == 0) logits[(size_t)wave * HH + h] = sum;
}

// -------- per-dst-node softmax + gather-aggregate (wave per node, no atomics) ----
__global__ __launch_bounds__(256) void node_gat(
    const int* __restrict__ offs, const int* __restrict__ eids,
    const int* __restrict__ src, const bf16* __restrict__ fs,
    const float* __restrict__ logits, float* __restrict__ acc,
    int n_dst, int accumulate) {
  int wave = blockIdx.x * 4 + (threadIdx.x >> 6);
  if (wave >= n_dst) return;
  int lane = threadIdx.x & 63;
  int h = lane >> 3, sub = lane & 7;
  int off = h * DD + sub * 4;
  int e0 = offs[wave], e1 = offs[wave + 1];

  // online softmax denominator over this node's in-edges (per head)
  float m = -1e30f, den = 0.f;
  for (int e = e0; e < e1; ++e) {
    float lg = logits[(size_t)eids[e] * HH + h];
    if (lg > m) { den *= __expf(m - lg); m = lg; }
    den += __expf(lg - m);
  }
  float inv = (den > 0.f) ? 1.f / den : 0.f;

  float4 a = make_float4(0.f, 0.f, 0.f, 0.f);
  for (int e = e0; e < e1; ++e) {
    int eid = eids[e];
    int s = src[eid];
    float alpha = __expf(logits[(size_t)eid * HH + h] - m) * inv;
    ushort4 us = *(const ushort4*)((const unsigned short*)fs + (size_t)s * CC + off);
    a.x += alpha * bu2f(us.x);
    a.y += alpha * bu2f(us.y);
    a.z += alpha * bu2f(us.z);
    a.w += alpha * bu2f(us.w);
  }
  float* p = acc + (size_t)wave * CC + off;
  if (accumulate) {
    float4 prev = *(const float4*)p;
    a.x += prev.x; a.y += prev.y; a.z += prev.z; a.w += prev.w;
  }
  *(float4*)p = a;
}

// -------- scale + ReLU -> bf16 node state; optionally emit f32 to d_out --------
__global__ __launch_bounds__(256) void finalize_k(
    const float* __restrict__ acc, float scale, bf16* __restrict__ hcur,
    float* __restrict__ outf, int n) {
  int i = blockIdx.x * 256 + threadIdx.x;
  if (i >= n) return;
  float v = acc[i] * scale;
  v = v > 0.f ? v : 0.f;
  hcur[i] = __float2bfloat16(v);
  if (outf) outf[i] = v;
}

extern "C" void kernel_launch(void* const* d_in, const int* in_sizes, int n_in,
                              void* d_out, int out_size, void* d_ws, size_t ws_size,
                              hipStream_t stream) {
  const float* x_tile = (const float*)d_in[0];
  const float* x_poi  = (const float*)d_in[1];
  const int* src_road = (const int*)d_in[2];
  const int* dst_road = (const int*)d_in[3];
  const int* src_tb   = (const int*)d_in[4];
  const int* dst_tb   = (const int*)d_in[5];
  const int* src_ct   = (const int*)d_in[6];
  const int* dst_ct   = (const int*)d_in[7];
  const float* Wsrc[3] = {(const float*)d_in[8],  (const float*)d_in[13], (const float*)d_in[18]};
  const float* bsrc[3] = {(const float*)d_in[9],  (const float*)d_in[14], (const float*)d_in[19]};
  const float* Wdst[3] = {(const float*)d_in[10], (const float*)d_in[15], (const float*)d_in[20]};
  const float* bdst[3] = {(const float*)d_in[11], (const float*)d_in[16], (const float*)d_in[21]};
  const float* attn[3] = {(const float*)d_in[12], (const float*)d_in[17], (const float*)d_in[22]};

  // workspace layout (~218 MB):
  // tacc, pacc : 2 x 50000*256 f32  (102.4 MB)
  // ht, hp     : 2 x 50000*256 bf16 (51.2 MB)
  // fs, fd     : 2 x 50000*256 bf16 (51.2 MB)
  // logits     : 200000*8 f32       (6.4 MB)
  // CSR x3     : off(50001) + tmp(50000) + eids(200000) ints (~3.6 MB)
  float* tacc = (float*)d_ws;
  float* pacc = tacc + (size_t)NT * CC;
  bf16* ht    = (bf16*)(pacc + (size_t)NP * CC);
  bf16* hp    = ht + (size_t)NT * CC;
  bf16* fs    = hp + (size_t)NP * CC;
  bf16* fd    = fs + (size_t)NT * CC;
  float* logits = (float*)(fd + (size_t)NT * CC);
  int* csr = (int*)(logits + (size_t)NE * HH);
  int* off3[3], *tmp3[3], *eids3[3];
  for (int r = 0; r < 3; r++) {
    off3[r]  = csr;            csr += NT + 1;
    tmp3[r]  = csr;            csr += NT;
    eids3[r] = csr;            csr += NE;
  }

  // convert f32 inputs to bf16 node states
  cvt_f2b<<<(NT * 128 + 255) / 256, 256, 0, stream>>>(x_tile, ht, NT * 128);
  cvt_f2b<<<(NP * 128 + 255) / 256, 256, 0, stream>>>(x_poi, hp, NP * 128);

  // build CSR for the 3 relations (graph is static across layers)
  const int* dsts[3] = {dst_road, dst_tb, dst_ct};
  for (int r = 0; r < 3; r++) {
    zero_i<<<(NT + 255) / 256, 256, 0, stream>>>(tmp3[r], NT);
    hist_k<<<(NE + 255) / 256, 256, 0, stream>>>(dsts[r], tmp3[r]);
    scan_k<<<1, 1024, 0, stream>>>(tmp3[r], off3[r], NT);
    copy_i<<<(NT + 255) / 256, 256, 0, stream>>>(off3[r], tmp3[r], NT);
    fill_k<<<(NE + 255) / 256, 256, 0, stream>>>(dsts[r], tmp3[r], eids3[r]);
  }

  for (int l = 0; l < 3; l++) {
    int K = (l == 0) ? 128 : 256;

    struct Rel {
      const bf16* hs; const bf16* hd;
      const int* s; const int* d;
      const int* off; const int* eids;
      float* acc; int n_src; int n_dst; int accumulate;
    };
    Rel rels[3] = {
      {ht, ht, src_road, dst_road, off3[0], eids3[0], tacc, NT, NT, 0},
      {hp, ht, src_tb,   dst_tb,   off3[1], eids3[1], tacc, NP, NT, 1},
      {ht, hp, src_ct,   dst_ct,   off3[2], eids3[2], pacc, NT, NP, 0},
    };

    for (int r = 0; r < 3; r++) {
      const float* Ws = Wsrc[l] + (size_t)r * K * CC;
      const float* bs = bsrc[l] + (size_t)r * CC;
      const float* Wd = Wdst[l] + (size_t)r * K * CC;
      const float* bd = bdst[l] + (size_t)r * CC;
      const float* at = attn[l] + (size_t)r * CC;

      dim3 gs((rels[r].n_src + 63) / 64, 4);
      gemm_bias<<<gs, 256, 0, stream>>>(rels[r].hs, Ws, bs, fs, rels[r].n_src, K);
      dim3 gd((rels[r].n_dst + 63) / 64, 4);
      gemm_bias<<<gd, 256, 0, stream>>>(rels[r].hd, Wd, bd, fd, rels[r].n_dst, K);

      edge_logits<<<(NE * 64) / 256, 256, 0, stream>>>(rels[r].s, rels[r].d, fs, fd, at, logits);
      node_gat<<<(rels[r].n_dst + 3) / 4, 256, 0, stream>>>(
          rels[r].off, rels[r].eids, rels[r].s, fs, logits,
          rels[r].acc, rels[r].n_dst, rels[r].accumulate);
    }

    float st = (l == 1) ? 0.5f : 1.0f;
    float* outT = (l == 2) ? (float*)d_out : nullptr;
    float* outP = (l == 2) ? ((float*)d_out + (size_t)NT * CC) : nullptr;
    finalize_k<<<(NT * CC + 255) / 256, 256, 0, stream>>>(tacc, st, ht, outT, NT * CC);
    finalize_k<<<(NP * CC + 255) / 256, 256, 0, stream>>>(pacc, 1.0f, hp, outP, NP * CC);
  }
}

// Round 4
// 1879.728 us; speedup vs baseline: 4.2602x; 1.4531x over previous
//
#include <hip/hip_runtime.h>
#include <hip/hip_bf16.h>

typedef __hip_bfloat16 bf16;

#define NT 50000
#define NP 50000
#define NE 200000
#define HH 8
#define DD 32
#define CC 256   // H*D

#define BM 128
#define BN 128
#define BK 32

typedef short s8v __attribute__((ext_vector_type(8)));   // 8 bf16 (4 VGPRs)
typedef float f4v __attribute__((ext_vector_type(4)));   // 4 f32 acc

__device__ __forceinline__ float bu2f(unsigned short u) {
  return __uint_as_float(((unsigned)u) << 16);
}

__device__ __forceinline__ void gload_lds16(const void* g, void* l) {
  __builtin_amdgcn_global_load_lds(
      (const __attribute__((address_space(1))) void*)g,
      (__attribute__((address_space(3))) void*)l, 16, 0, 0);
}

// -------- utility converts --------
__global__ __launch_bounds__(256) void cvt_f2b(const float* __restrict__ in,
                                               bf16* __restrict__ out, int n) {
  int i = blockIdx.x * 256 + threadIdx.x;
  if (i < n) out[i] = __float2bfloat16(in[i]);
}

// W (3,K,256) f32 -> Wt (3,256,K) bf16 (transposed per relation)
__global__ __launch_bounds__(256) void wt_cvt(const float* __restrict__ W,
                                              bf16* __restrict__ Wt, int K) {
  int idx = blockIdx.x * 256 + threadIdx.x;
  int total = 3 * 256 * K;
  if (idx >= total) return;
  int r = idx / (256 * K);
  int rem = idx - r * 256 * K;
  int n = rem / K;
  int k = rem - n * K;
  Wt[idx] = __float2bfloat16(W[((size_t)r * K + k) * 256 + n]);
}

__global__ __launch_bounds__(256) void zero_i(int* __restrict__ p, int n) {
  int i = blockIdx.x * 256 + threadIdx.x;
  if (i < n) p[i] = 0;
}

__global__ __launch_bounds__(256) void copy_i(const int* __restrict__ a,
                                              int* __restrict__ b, int n) {
  int i = blockIdx.x * 256 + threadIdx.x;
  if (i < n) b[i] = a[i];
}

// -------- CSR build --------
__global__ __launch_bounds__(256) void hist_k(const int* __restrict__ dst,
                                              int* __restrict__ deg) {
  int e = blockIdx.x * 256 + threadIdx.x;
  if (e < NE) atomicAdd(&deg[dst[e]], 1);
}

__global__ __launch_bounds__(1024) void scan_k(const int* __restrict__ deg,
                                               int* __restrict__ off, int n) {
  __shared__ int buf[1024];
  __shared__ int carry_s;
  int tid = threadIdx.x;
  if (tid == 0) carry_s = 0;
  __syncthreads();
  for (int base = 0; base < n; base += 1024) {
    int i = base + tid;
    int v = (i < n) ? deg[i] : 0;
    buf[tid] = v;
    __syncthreads();
    for (int s = 1; s < 1024; s <<= 1) {
      int t = (tid >= s) ? buf[tid - s] : 0;
      __syncthreads();
      buf[tid] += t;
      __syncthreads();
    }
    int carry = carry_s;
    if (i < n) off[i] = carry + buf[tid] - v;
    __syncthreads();
    if (tid == 1023) carry_s = carry + buf[1023];
    __syncthreads();
  }
  if (tid == 0) off[n] = carry_s;
}

__global__ __launch_bounds__(256) void fill_k(const int* __restrict__ dst,
                                              int* __restrict__ cursor,
                                              int* __restrict__ eids) {
  int e = blockIdx.x * 256 + threadIdx.x;
  if (e < NE) {
    int p = atomicAdd(&cursor[dst[e]], 1);
    eids[p] = e;
  }
}

// -------- MFMA GEMM: C[m,n] = sum_k A[m,k]*Bt[n,k] + bias[n]; N=256 --------
// A bf16 (M x K), Bt bf16 (256 x K), bias f32, out bf16 (M x 256)
// grid: (bn=2, bm=ceil(M/128)); 256 threads = 4 waves (2x2), 64x64 out each.
__global__ __launch_bounds__(256) void gemm_mfma(
    const bf16* __restrict__ A, const bf16* __restrict__ Bt,
    const float* __restrict__ bias, bf16* __restrict__ Cout, int M, int K) {
  __shared__ short Als[2][BM * BK];   // [row][k] 8KB per buf
  __shared__ short Bls[2][BN * BK];   // [col][k]
  int bn = blockIdx.x, bm = blockIdx.y;
  int t = threadIdx.x;
  int lane = t & 63;
  int wid = t >> 6;
  int wm = wid >> 1, wn = wid & 1;
  int row0 = bm * BM, col0 = bn * BN;

  f4v acc[4][4] = {};

  const bf16* Abase = A + (size_t)row0 * K;
  const bf16* Bbase = Bt + (size_t)col0 * K;
  int wbase = (t & ~63);  // wid*64

  // stage K-step ks into buffer buf (A: 512 slots of 16B, B: 512 slots)
  auto stage = [&](int buf, int ks) {
    int kofs = ks * BK;
    #pragma unroll
    for (int j = 0; j < 2; j++) {
      int slot = j * 256 + t;
      int r = slot >> 2;
      int k0 = (slot & 3) * 8;
      gload_lds16(Abase + (size_t)r * K + kofs + k0,
                  &Als[buf][(j * 256 + wbase) * 8]);
    }
    #pragma unroll
    for (int j = 0; j < 2; j++) {
      int slot = j * 256 + t;
      int r = slot >> 2;
      int k0 = (slot & 3) * 8;
      gload_lds16(Bbase + (size_t)r * K + kofs + k0,
                  &Bls[buf][(j * 256 + wbase) * 8]);
    }
  };

  int nk = K / BK;
  int cur = 0;
  stage(0, 0);
  __syncthreads();

  for (int ks = 0; ks < nk; ks++) {
    if (ks + 1 < nk) stage(cur ^ 1, ks + 1);
    int kq = (lane >> 4) * 8;
    int rr = lane & 15;
    s8v af[4], bfv[4];
    #pragma unroll
    for (int mi = 0; mi < 4; mi++)
      af[mi] = *(const s8v*)&Als[cur][(wm * 64 + mi * 16 + rr) * BK + kq];
    #pragma unroll
    for (int ni = 0; ni < 4; ni++)
      bfv[ni] = *(const s8v*)&Bls[cur][(wn * 64 + ni * 16 + rr) * BK + kq];
    #pragma unroll
    for (int mi = 0; mi < 4; mi++)
      #pragma unroll
      for (int ni = 0; ni < 4; ni++)
        acc[mi][ni] = __builtin_amdgcn_mfma_f32_16x16x32_bf16(
            af[mi], bfv[ni], acc[mi][ni], 0, 0, 0);
    __syncthreads();
    cur ^= 1;
  }

  #pragma unroll
  for (int mi = 0; mi < 4; mi++) {
    int row = row0 + wm * 64 + mi * 16 + (lane >> 4) * 4;
    #pragma unroll
    for (int ni = 0; ni < 4; ni++) {
      int col = col0 + wn * 64 + ni * 16 + (lane & 15);
      float bv = bias[col];
      #pragma unroll
      for (int r = 0; r < 4; r++) {
        if (row + r < M)
          Cout[(size_t)(row + r) * CC + col] = __float2bfloat16(acc[mi][ni][r] + bv);
      }
    }
  }
}

// -------- edge logits (wave per edge; no atomics) --------
__global__ __launch_bounds__(256) void edge_logits(
    const int* __restrict__ src, const int* __restrict__ dst,
    const bf16* __restrict__ fs, const bf16* __restrict__ fd,
    const float* __restrict__ attn, float* __restrict__ logits) {
  int wave = (blockIdx.x * 256 + threadIdx.x) >> 6;
  if (wave >= NE) return;
  int lane = threadIdx.x & 63;
  int h = lane >> 3, sub = lane & 7;
  int s = src[wave], d = dst[wave];
  int off = h * DD + sub * 4;
  ushort4 us = *(const ushort4*)((const unsigned short*)fs + (size_t)s * CC + off);
  ushort4 ud = *(const ushort4*)((const unsigned short*)fd + (size_t)d * CC + off);
  float4 a4 = *(const float4*)(attn + off);
  float sum = 0.f;
  {
    float e0 = bu2f(us.x) + bu2f(ud.x); e0 = e0 > 0.f ? e0 : 0.2f * e0; sum += e0 * a4.x;
    float e1 = bu2f(us.y) + bu2f(ud.y); e1 = e1 > 0.f ? e1 : 0.2f * e1; sum += e1 * a4.y;
    float e2 = bu2f(us.z) + bu2f(ud.z); e2 = e2 > 0.f ? e2 : 0.2f * e2; sum += e2 * a4.z;
    float e3 = bu2f(us.w) + bu2f(ud.w); e3 = e3 > 0.f ? e3 : 0.2f * e3; sum += e3 * a4.w;
  }
  sum += __shfl_xor(sum, 1);
  sum += __shfl_xor(sum, 2);
  sum += __shfl_xor(sum, 4);
  if (sub == 0) logits[(size_t)wave * HH + h] = sum;
}

// -------- per-dst-node softmax + gather-aggregate (wave per node) --------
__global__ __launch_bounds__(256) void node_gat(
    const int* __restrict__ offs, const int* __restrict__ eids,
    const int* __restrict__ src, const bf16* __restrict__ fs,
    const float* __restrict__ logits, float* __restrict__ acc,
    int n_dst, int accumulate) {
  int wave = blockIdx.x * 4 + (threadIdx.x >> 6);
  if (wave >= n_dst) return;
  int lane = threadIdx.x & 63;
  int h = lane >> 3, sub = lane & 7;
  int off = h * DD + sub * 4;
  int e0 = offs[wave], e1 = offs[wave + 1];

  float m = -1e30f, den = 0.f;
  for (int e = e0; e < e1; ++e) {
    float lg = logits[(size_t)eids[e] * HH + h];
    if (lg > m) { den *= __expf(m - lg); m = lg; }
    den += __expf(lg - m);
  }
  float inv = (den > 0.f) ? 1.f / den : 0.f;

  float4 a = make_float4(0.f, 0.f, 0.f, 0.f);
  for (int e = e0; e < e1; ++e) {
    int eid = eids[e];
    int s = src[eid];
    float alpha = __expf(logits[(size_t)eid * HH + h] - m) * inv;
    ushort4 us = *(const ushort4*)((const unsigned short*)fs + (size_t)s * CC + off);
    a.x += alpha * bu2f(us.x);
    a.y += alpha * bu2f(us.y);
    a.z += alpha * bu2f(us.z);
    a.w += alpha * bu2f(us.w);
  }
  float* p = acc + (size_t)wave * CC + off;
  if (accumulate) {
    float4 prev = *(const float4*)p;
    a.x += prev.x; a.y += prev.y; a.z += prev.z; a.w += prev.w;
  }
  *(float4*)p = a;
}

// -------- scale + ReLU -> bf16 node state; optionally emit f32 to d_out ----
__global__ __launch_bounds__(256) void finalize_k(
    const float* __restrict__ acc, float scale, bf16* __restrict__ hcur,
    float* __restrict__ outf, int n) {
  int i = blockIdx.x * 256 + threadIdx.x;
  if (i >= n) return;
  float v = acc[i] * scale;
  v = v > 0.f ? v : 0.f;
  hcur[i] = __float2bfloat16(v);
  if (outf) outf[i] = v;
}

extern "C" void kernel_launch(void* const* d_in, const int* in_sizes, int n_in,
                              void* d_out, int out_size, void* d_ws, size_t ws_size,
                              hipStream_t stream) {
  const float* x_tile = (const float*)d_in[0];
  const float* x_poi  = (const float*)d_in[1];
  const int* src_road = (const int*)d_in[2];
  const int* dst_road = (const int*)d_in[3];
  const int* src_tb   = (const int*)d_in[4];
  const int* dst_tb   = (const int*)d_in[5];
  const int* src_ct   = (const int*)d_in[6];
  const int* dst_ct   = (const int*)d_in[7];
  const float* Wsrc[3] = {(const float*)d_in[8],  (const float*)d_in[13], (const float*)d_in[18]};
  const float* bsrc[3] = {(const float*)d_in[9],  (const float*)d_in[14], (const float*)d_in[19]};
  const float* Wdst[3] = {(const float*)d_in[10], (const float*)d_in[15], (const float*)d_in[20]};
  const float* bdst[3] = {(const float*)d_in[11], (const float*)d_in[16], (const float*)d_in[21]};
  const float* attn[3] = {(const float*)d_in[12], (const float*)d_in[17], (const float*)d_in[22]};

  // workspace layout (~220 MB)
  float* tacc = (float*)d_ws;
  float* pacc = tacc + (size_t)NT * CC;
  bf16* ht    = (bf16*)(pacc + (size_t)NP * CC);
  bf16* hp    = ht + (size_t)NT * CC;
  bf16* fs    = hp + (size_t)NP * CC;
  bf16* fd    = fs + (size_t)NT * CC;
  float* logits = (float*)(fd + (size_t)NT * CC);
  int* csr = (int*)(logits + (size_t)NE * HH);
  int* off3[3], *tmp3[3], *eids3[3];
  for (int r = 0; r < 3; r++) {
    off3[r]  = csr;            csr += NT + 1;
    tmp3[r]  = csr;            csr += NT;
    eids3[r] = csr;            csr += NE;
  }
  // bf16 transposed weights, 16B aligned
  uintptr_t wp = ((uintptr_t)csr + 63) & ~(uintptr_t)63;
  bf16* wsrc_t[3], *wdst_t[3];
  {
    bf16* w = (bf16*)wp;
    for (int l = 0; l < 3; l++) {
      int K = (l == 0) ? 128 : 256;
      wsrc_t[l] = w; w += (size_t)3 * 256 * K;
      wdst_t[l] = w; w += (size_t)3 * 256 * K;
    }
  }

  // convert f32 inputs to bf16 node states
  cvt_f2b<<<(NT * 128 + 255) / 256, 256, 0, stream>>>(x_tile, ht, NT * 128);
  cvt_f2b<<<(NP * 128 + 255) / 256, 256, 0, stream>>>(x_poi, hp, NP * 128);

  // convert + transpose all weights to bf16 (graph is static; do every call)
  for (int l = 0; l < 3; l++) {
    int K = (l == 0) ? 128 : 256;
    int tot = 3 * 256 * K;
    wt_cvt<<<(tot + 255) / 256, 256, 0, stream>>>(Wsrc[l], wsrc_t[l], K);
    wt_cvt<<<(tot + 255) / 256, 256, 0, stream>>>(Wdst[l], wdst_t[l], K);
  }

  // build CSR for the 3 relations
  const int* dsts[3] = {dst_road, dst_tb, dst_ct};
  for (int r = 0; r < 3; r++) {
    zero_i<<<(NT + 255) / 256, 256, 0, stream>>>(tmp3[r], NT);
    hist_k<<<(NE + 255) / 256, 256, 0, stream>>>(dsts[r], tmp3[r]);
    scan_k<<<1, 1024, 0, stream>>>(tmp3[r], off3[r], NT);
    copy_i<<<(NT + 255) / 256, 256, 0, stream>>>(off3[r], tmp3[r], NT);
    fill_k<<<(NE + 255) / 256, 256, 0, stream>>>(dsts[r], tmp3[r], eids3[r]);
  }

  for (int l = 0; l < 3; l++) {
    int K = (l == 0) ? 128 : 256;

    struct Rel {
      const bf16* hs; const bf16* hd;
      const int* s;
      const int* off; const int* eids;
      float* acc; int n_src; int n_dst; int accumulate;
    };
    Rel rels[3] = {
      {ht, ht, src_road, off3[0], eids3[0], tacc, NT, NT, 0},
      {hp, ht, src_tb,   off3[1], eids3[1], tacc, NP, NT, 1},
      {ht, hp, src_ct,   off3[2], eids3[2], pacc, NT, NP, 0},
    };

    for (int r = 0; r < 3; r++) {
      const bf16* Wst = wsrc_t[l] + (size_t)r * 256 * K;
      const bf16* Wdt = wdst_t[l] + (size_t)r * 256 * K;
      const float* bs = bsrc[l] + (size_t)r * CC;
      const float* bd = bdst[l] + (size_t)r * CC;
      const float* at = attn[l] + (size_t)r * CC;

      dim3 gs(2, (rels[r].n_src + BM - 1) / BM);
      gemm_mfma<<<gs, 256, 0, stream>>>(rels[r].hs, Wst, bs, fs, rels[r].n_src, K);
      dim3 gd(2, (rels[r].n_dst + BM - 1) / BM);
      gemm_mfma<<<gd, 256, 0, stream>>>(rels[r].hd, Wdt, bd, fd, rels[r].n_dst, K);

      edge_logits<<<(NE * 64) / 256, 256, 0, stream>>>(
          rels[r].s, dsts[r], fs, fd, at, logits);
      node_gat<<<(rels[r].n_dst + 3) / 4, 256, 0, stream>>>(
          rels[r].off, rels[r].eids, rels[r].s, fs, logits,
          rels[r].acc, rels[r].n_dst, rels[r].accumulate);
    }

    float st = (l == 1) ? 0.5f : 1.0f;
    float* outT = (l == 2) ? (float*)d_out : nullptr;
    float* outP = (l == 2) ? ((float*)d_out + (size_t)NT * CC) : nullptr;
    finalize_k<<<(NT * CC + 255) / 256, 256, 0, stream>>>(tacc, st, ht, outT, NT * CC);
    finalize_k<<<(NP * CC + 255) / 256, 256, 0, stream>>>(pacc, 1.0f, hp, outP, NP * CC);
  }
}

// Round 5
// 1556.444 us; speedup vs baseline: 5.1451x; 1.2077x over previous
//
#include <hip/hip_runtime.h>
#include <hip/hip_bf16.h>

typedef __hip_bfloat16 bf16;

#define NT 50000
#define NP 50000
#define NE 200000
#define HH 8
#define DD 32
#define CC 256   // H*D

#define BM 128
#define BN 128
#define BK 32

typedef short s8v __attribute__((ext_vector_type(8)));   // 8 bf16 (4 VGPRs)
typedef float f4v __attribute__((ext_vector_type(4)));   // 4 f32 acc

__device__ __forceinline__ float bu2f(unsigned short u) {
  return __uint_as_float(((unsigned)u) << 16);
}
__device__ __forceinline__ unsigned short f2bu(float x) {
  bf16 b = __float2bfloat16(x);
  return *(unsigned short*)&b;
}

__device__ __forceinline__ void gload_lds16(const void* g, void* l) {
  __builtin_amdgcn_global_load_lds(
      (const __attribute__((address_space(1))) void*)g,
      (__attribute__((address_space(3))) void*)l, 16, 0, 0);
}

// -------- utility converts --------
__global__ __launch_bounds__(256) void cvt_f2b(const float* __restrict__ in,
                                               bf16* __restrict__ out, int n) {
  int i = blockIdx.x * 256 + threadIdx.x;
  if (i < n) out[i] = __float2bfloat16(in[i]);
}

// W (3,K,256) f32 -> Wt (3,256,K) bf16 (transposed per relation)
__global__ __launch_bounds__(256) void wt_cvt(const float* __restrict__ W,
                                              bf16* __restrict__ Wt, int K) {
  int idx = blockIdx.x * 256 + threadIdx.x;
  int total = 3 * 256 * K;
  if (idx >= total) return;
  int r = idx / (256 * K);
  int rem = idx - r * 256 * K;
  int n = rem / K;
  int k = rem - n * K;
  Wt[idx] = __float2bfloat16(W[((size_t)r * K + k) * 256 + n]);
}

__global__ __launch_bounds__(256) void zero_i(int* __restrict__ p, int n) {
  int i = blockIdx.x * 256 + threadIdx.x;
  if (i < n) p[i] = 0;
}

__global__ __launch_bounds__(256) void copy_i(const int* __restrict__ a,
                                              int* __restrict__ b, int n) {
  int i = blockIdx.x * 256 + threadIdx.x;
  if (i < n) b[i] = a[i];
}

// -------- CSR build --------
__global__ __launch_bounds__(256) void hist_k(const int* __restrict__ dst,
                                              int* __restrict__ deg) {
  int e = blockIdx.x * 256 + threadIdx.x;
  if (e < NE) atomicAdd(&deg[dst[e]], 1);
}

// single-block exclusive scan, thread-serial chunks + one 1024-wide scan
__global__ __launch_bounds__(1024) void scan_k(const int* __restrict__ deg,
                                               int* __restrict__ off, int n) {
  __shared__ int sums[1024];
  int tid = threadIdx.x;
  int chunk = (n + 1023) >> 10;
  int base = tid * chunk;
  int s = 0;
  for (int i = 0; i < chunk; i++) {
    int idx = base + i;
    if (idx < n) s += deg[idx];
  }
  sums[tid] = s;
  __syncthreads();
  // Hillis-Steele inclusive scan over 1024 thread sums
  for (int st = 1; st < 1024; st <<= 1) {
    int v = (tid >= st) ? sums[tid - st] : 0;
    __syncthreads();
    sums[tid] += v;
    __syncthreads();
  }
  int excl = (tid == 0) ? 0 : sums[tid - 1];
  for (int i = 0; i < chunk; i++) {
    int idx = base + i;
    if (idx < n) { off[idx] = excl; excl += deg[idx]; }
  }
  if (tid == 1023) off[n] = sums[1023];
}

__global__ __launch_bounds__(256) void fill_k(const int* __restrict__ dst,
                                              int* __restrict__ cursor,
                                              int* __restrict__ eids) {
  int e = blockIdx.x * 256 + threadIdx.x;
  if (e < NE) {
    int p = atomicAdd(&cursor[dst[e]], 1);
    eids[p] = e;
  }
}

// -------- MFMA GEMM: C[m,n] = sum_k A[m,k]*Bt[n,k] + bias[n]; N=256 --------
__global__ __launch_bounds__(256) void gemm_mfma(
    const bf16* __restrict__ A, const bf16* __restrict__ Bt,
    const float* __restrict__ bias, bf16* __restrict__ Cout, int M, int K) {
  __shared__ short Als[2][BM * BK];
  __shared__ short Bls[2][BN * BK];
  int bn = blockIdx.x, bm = blockIdx.y;
  int t = threadIdx.x;
  int lane = t & 63;
  int wid = t >> 6;
  int wm = wid >> 1, wn = wid & 1;
  int row0 = bm * BM, col0 = bn * BN;

  f4v acc[4][4] = {};

  const bf16* Abase = A + (size_t)row0 * K;
  const bf16* Bbase = Bt + (size_t)col0 * K;
  int wbase = (t & ~63);

  auto stage = [&](int buf, int ks) {
    int kofs = ks * BK;
    #pragma unroll
    for (int j = 0; j < 2; j++) {
      int slot = j * 256 + t;
      int r = slot >> 2;
      int k0 = (slot & 3) * 8;
      gload_lds16(Abase + (size_t)r * K + kofs + k0,
                  &Als[buf][(j * 256 + wbase) * 8]);
    }
    #pragma unroll
    for (int j = 0; j < 2; j++) {
      int slot = j * 256 + t;
      int r = slot >> 2;
      int k0 = (slot & 3) * 8;
      gload_lds16(Bbase + (size_t)r * K + kofs + k0,
                  &Bls[buf][(j * 256 + wbase) * 8]);
    }
  };

  int nk = K / BK;
  int cur = 0;
  stage(0, 0);
  __syncthreads();

  for (int ks = 0; ks < nk; ks++) {
    if (ks + 1 < nk) stage(cur ^ 1, ks + 1);
    int kq = (lane >> 4) * 8;
    int rr = lane & 15;
    s8v af[4], bfv[4];
    #pragma unroll
    for (int mi = 0; mi < 4; mi++)
      af[mi] = *(const s8v*)&Als[cur][(wm * 64 + mi * 16 + rr) * BK + kq];
    #pragma unroll
    for (int ni = 0; ni < 4; ni++)
      bfv[ni] = *(const s8v*)&Bls[cur][(wn * 64 + ni * 16 + rr) * BK + kq];
    #pragma unroll
    for (int mi = 0; mi < 4; mi++)
      #pragma unroll
      for (int ni = 0; ni < 4; ni++)
        acc[mi][ni] = __builtin_amdgcn_mfma_f32_16x16x32_bf16(
            af[mi], bfv[ni], acc[mi][ni], 0, 0, 0);
    __syncthreads();
    cur ^= 1;
  }

  #pragma unroll
  for (int mi = 0; mi < 4; mi++) {
    int row = row0 + wm * 64 + mi * 16 + (lane >> 4) * 4;
    #pragma unroll
    for (int ni = 0; ni < 4; ni++) {
      int col = col0 + wn * 64 + ni * 16 + (lane & 15);
      float bv = bias[col];
      #pragma unroll
      for (int r = 0; r < 4; r++) {
        if (row + r < M)
          Cout[(size_t)(row + r) * CC + col] = __float2bfloat16(acc[mi][ni][r] + bv);
      }
    }
  }
}

// -------- fused per-dst-node GATv2: logits + softmax + gather + epilogue ----
// wave per dst node. mode 0: write acc (f32). mode 1: acc+=, *scale, relu ->
// bf16 hnew (+f32 outf). mode 2: relu -> bf16 hnew (+f32 outf), no acc.
__global__ __launch_bounds__(256) void node_gat_f(
    const int* __restrict__ offs, const int* __restrict__ eids,
    const int* __restrict__ src, const bf16* __restrict__ fs,
    const bf16* __restrict__ fd, const float* __restrict__ attn,
    float* __restrict__ acc, bf16* __restrict__ hnew,
    float* __restrict__ outf, float scale, int n_dst, int mode) {
  int wave = blockIdx.x * 4 + (threadIdx.x >> 6);
  if (wave >= n_dst) return;
  int lane = threadIdx.x & 63;
  int h = lane >> 3, sub = lane & 7;
  int off = h * DD + sub * 4;

  ushort4 ud = *(const ushort4*)((const unsigned short*)fd + (size_t)wave * CC + off);
  float d0 = bu2f(ud.x), d1 = bu2f(ud.y), d2 = bu2f(ud.z), d3 = bu2f(ud.w);
  float4 at = *(const float4*)(attn + off);

  int e0 = offs[wave], e1 = offs[wave + 1];

  // pass 1: online softmax max + denominator
  float m = -1e30f, den = 0.f;
  for (int e = e0; e < e1; ++e) {
    int s = src[eids[e]];
    ushort4 us = *(const ushort4*)((const unsigned short*)fs + (size_t)s * CC + off);
    float t0 = bu2f(us.x) + d0; t0 = t0 > 0.f ? t0 : 0.2f * t0;
    float t1 = bu2f(us.y) + d1; t1 = t1 > 0.f ? t1 : 0.2f * t1;
    float t2 = bu2f(us.z) + d2; t2 = t2 > 0.f ? t2 : 0.2f * t2;
    float t3 = bu2f(us.w) + d3; t3 = t3 > 0.f ? t3 : 0.2f * t3;
    float lg = t0 * at.x + t1 * at.y + t2 * at.z + t3 * at.w;
    lg += __shfl_xor(lg, 1);
    lg += __shfl_xor(lg, 2);
    lg += __shfl_xor(lg, 4);
    if (lg > m) { den *= __expf(m - lg); m = lg; }
    den += __expf(lg - m);
  }
  float inv = (den > 0.f) ? 1.f / den : 0.f;

  // pass 2: recompute logit (fs row L2-hot), accumulate weighted sum
  float a0 = 0.f, a1 = 0.f, a2 = 0.f, a3 = 0.f;
  for (int e = e0; e < e1; ++e) {
    int s = src[eids[e]];
    ushort4 us = *(const ushort4*)((const unsigned short*)fs + (size_t)s * CC + off);
    float f0 = bu2f(us.x), f1 = bu2f(us.y), f2 = bu2f(us.z), f3 = bu2f(us.w);
    float t0 = f0 + d0; t0 = t0 > 0.f ? t0 : 0.2f * t0;
    float t1 = f1 + d1; t1 = t1 > 0.f ? t1 : 0.2f * t1;
    float t2 = f2 + d2; t2 = t2 > 0.f ? t2 : 0.2f * t2;
    float t3 = f3 + d3; t3 = t3 > 0.f ? t3 : 0.2f * t3;
    float lg = t0 * at.x + t1 * at.y + t2 * at.z + t3 * at.w;
    lg += __shfl_xor(lg, 1);
    lg += __shfl_xor(lg, 2);
    lg += __shfl_xor(lg, 4);
    float alpha = __expf(lg - m) * inv;
    a0 += alpha * f0; a1 += alpha * f1; a2 += alpha * f2; a3 += alpha * f3;
  }

  size_t base = (size_t)wave * CC + off;
  if (mode == 0) {
    *(float4*)(acc + base) = make_float4(a0, a1, a2, a3);
  } else {
    if (mode == 1) {
      float4 p = *(const float4*)(acc + base);
      a0 += p.x; a1 += p.y; a2 += p.z; a3 += p.w;
    }
    a0 *= scale; a1 *= scale; a2 *= scale; a3 *= scale;
    a0 = a0 > 0.f ? a0 : 0.f;
    a1 = a1 > 0.f ? a1 : 0.f;
    a2 = a2 > 0.f ? a2 : 0.f;
    a3 = a3 > 0.f ? a3 : 0.f;
    ushort4 o = make_ushort4(f2bu(a0), f2bu(a1), f2bu(a2), f2bu(a3));
    *(ushort4*)((unsigned short*)hnew + base) = o;
    if (outf) *(float4*)(outf + base) = make_float4(a0, a1, a2, a3);
  }
}

extern "C" void kernel_launch(void* const* d_in, const int* in_sizes, int n_in,
                              void* d_out, int out_size, void* d_ws, size_t ws_size,
                              hipStream_t stream) {
  const float* x_tile = (const float*)d_in[0];
  const float* x_poi  = (const float*)d_in[1];
  const int* src_road = (const int*)d_in[2];
  const int* dst_road = (const int*)d_in[3];
  const int* src_tb   = (const int*)d_in[4];
  const int* dst_tb   = (const int*)d_in[5];
  const int* src_ct   = (const int*)d_in[6];
  const int* dst_ct   = (const int*)d_in[7];
  const float* Wsrc[3] = {(const float*)d_in[8],  (const float*)d_in[13], (const float*)d_in[18]};
  const float* bsrc[3] = {(const float*)d_in[9],  (const float*)d_in[14], (const float*)d_in[19]};
  const float* Wdst[3] = {(const float*)d_in[10], (const float*)d_in[15], (const float*)d_in[20]};
  const float* bdst[3] = {(const float*)d_in[11], (const float*)d_in[16], (const float*)d_in[21]};
  const float* attn[3] = {(const float*)d_in[12], (const float*)d_in[17], (const float*)d_in[22]};

  // workspace layout (~210 MB):
  // tacc               : NT*CC f32          (51.2 MB)
  // ht[2], hp[2]       : 4 x NT*CC bf16     (102.4 MB)
  // fs, fd             : 2 x NT*CC bf16     (51.2 MB)
  // CSR x3             : off + tmp + eids   (~3.6 MB)
  // bf16 Wt            : ~2 MB
  float* tacc = (float*)d_ws;
  bf16* hbuf = (bf16*)(tacc + (size_t)NT * CC);
  bf16* ht2[2] = {hbuf, hbuf + (size_t)NT * CC};
  bf16* hp2[2] = {hbuf + 2 * (size_t)NT * CC, hbuf + 3 * (size_t)NT * CC};
  bf16* fs = hbuf + 4 * (size_t)NT * CC;
  bf16* fd = fs + (size_t)NT * CC;
  int* csr = (int*)(fd + (size_t)NT * CC);
  int* off3[3], *tmp3[3], *eids3[3];
  for (int r = 0; r < 3; r++) {
    off3[r]  = csr;            csr += NT + 1;
    tmp3[r]  = csr;            csr += NT;
    eids3[r] = csr;            csr += NE;
  }
  uintptr_t wp = ((uintptr_t)csr + 63) & ~(uintptr_t)63;
  bf16* wsrc_t[3], *wdst_t[3];
  {
    bf16* w = (bf16*)wp;
    for (int l = 0; l < 3; l++) {
      int K = (l == 0) ? 128 : 256;
      wsrc_t[l] = w; w += (size_t)3 * 256 * K;
      wdst_t[l] = w; w += (size_t)3 * 256 * K;
    }
  }

  // convert f32 inputs to bf16 node states (buffer 0)
  cvt_f2b<<<(NT * 128 + 255) / 256, 256, 0, stream>>>(x_tile, ht2[0], NT * 128);
  cvt_f2b<<<(NP * 128 + 255) / 256, 256, 0, stream>>>(x_poi, hp2[0], NP * 128);

  // convert + transpose weights to bf16
  for (int l = 0; l < 3; l++) {
    int K = (l == 0) ? 128 : 256;
    int tot = 3 * 256 * K;
    wt_cvt<<<(tot + 255) / 256, 256, 0, stream>>>(Wsrc[l], wsrc_t[l], K);
    wt_cvt<<<(tot + 255) / 256, 256, 0, stream>>>(Wdst[l], wdst_t[l], K);
  }

  // build CSR for the 3 relations
  const int* dsts[3] = {dst_road, dst_tb, dst_ct};
  for (int r = 0; r < 3; r++) {
    zero_i<<<(NT + 255) / 256, 256, 0, stream>>>(tmp3[r], NT);
    hist_k<<<(NE + 255) / 256, 256, 0, stream>>>(dsts[r], tmp3[r]);
    scan_k<<<1, 1024, 0, stream>>>(tmp3[r], off3[r], NT);
    copy_i<<<(NT + 255) / 256, 256, 0, stream>>>(off3[r], tmp3[r], NT);
    fill_k<<<(NE + 255) / 256, 256, 0, stream>>>(dsts[r], tmp3[r], eids3[r]);
  }

  int cb = 0;  // current state buffer
  for (int l = 0; l < 3; l++) {
    int K = (l == 0) ? 128 : 256;
    bf16* ht_c = ht2[cb], *hp_c = hp2[cb];
    bf16* ht_n = ht2[cb ^ 1], *hp_n = hp2[cb ^ 1];
    float st = (l == 1) ? 0.5f : 1.0f;
    float* outT = (l == 2) ? (float*)d_out : nullptr;
    float* outP = (l == 2) ? ((float*)d_out + (size_t)NT * CC) : nullptr;

    struct Rel {
      const bf16* hs; const bf16* hd;
      const int* s;
      const int* off; const int* eids;
      bf16* hnew; float* outf; float scale; int mode;
    };
    Rel rels[3] = {
      {ht_c, ht_c, src_road, off3[0], eids3[0], nullptr, nullptr, 1.0f, 0},
      {hp_c, ht_c, src_tb,   off3[1], eids3[1], ht_n,    outT,    st,   1},
      {ht_c, hp_c, src_ct,   off3[2], eids3[2], hp_n,    outP,    1.0f, 2},
    };

    for (int r = 0; r < 3; r++) {
      const bf16* Wst = wsrc_t[l] + (size_t)r * 256 * K;
      const bf16* Wdt = wdst_t[l] + (size_t)r * 256 * K;
      const float* bs = bsrc[l] + (size_t)r * CC;
      const float* bd = bdst[l] + (size_t)r * CC;
      const float* at = attn[l] + (size_t)r * CC;

      dim3 gs(2, (NT + BM - 1) / BM);
      gemm_mfma<<<gs, 256, 0, stream>>>(rels[r].hs, Wst, bs, fs, NT, K);
      gemm_mfma<<<gs, 256, 0, stream>>>(rels[r].hd, Wdt, bd, fd, NT, K);

      node_gat_f<<<(NT + 3) / 4, 256, 0, stream>>>(
          rels[r].off, rels[r].eids, rels[r].s, fs, fd, at,
          tacc, rels[r].hnew, rels[r].outf, rels[r].scale, NT, rels[r].mode);
    }
    cb ^= 1;
  }
}

// Round 6
// 929.663 us; speedup vs baseline: 8.6139x; 1.6742x over previous
//
#include <hip/hip_runtime.h>
#include <hip/hip_bf16.h>

typedef __hip_bfloat16 bf16;

#define NT 50000
#define NP 50000
#define NE 200000
#define HH 8
#define DD 32
#define CC 256   // H*D
#define NBLK 196 // ceil(NT/256)

#define BM 128
#define BN 128
#define BK 32

typedef short s8v __attribute__((ext_vector_type(8)));   // 8 bf16 (4 VGPRs)
typedef float f4v __attribute__((ext_vector_type(4)));   // 4 f32 acc

__device__ __forceinline__ float bu2f(unsigned short u) {
  return __uint_as_float(((unsigned)u) << 16);
}
__device__ __forceinline__ unsigned short f2bu(float x) {
  bf16 b = __float2bfloat16(x);
  return *(unsigned short*)&b;
}

__device__ __forceinline__ void gload_lds16(const void* g, void* l) {
  __builtin_amdgcn_global_load_lds(
      (const __attribute__((address_space(1))) void*)g,
      (__attribute__((address_space(3))) void*)l, 16, 0, 0);
}

// -------- utility converts --------
__global__ __launch_bounds__(256) void cvt_f2b(const float* __restrict__ in,
                                               bf16* __restrict__ out, int n) {
  int i = blockIdx.x * 256 + threadIdx.x;
  if (i < n) out[i] = __float2bfloat16(in[i]);
}

// W (3,K,256) f32 -> Wt (3,256,K) bf16 (transposed per relation)
__global__ __launch_bounds__(256) void wt_cvt(const float* __restrict__ W,
                                              bf16* __restrict__ Wt, int K) {
  int idx = blockIdx.x * 256 + threadIdx.x;
  int total = 3 * 256 * K;
  if (idx >= total) return;
  int r = idx / (256 * K);
  int rem = idx - r * 256 * K;
  int n = rem / K;
  int k = rem - n * K;
  Wt[idx] = __float2bfloat16(W[((size_t)r * K + k) * 256 + n]);
}

__global__ __launch_bounds__(256) void zero_i(int* __restrict__ p, int n) {
  int i = blockIdx.x * 256 + threadIdx.x;
  if (i < n) p[i] = 0;
}

// -------- CSR build (batched over 3 relations via blockIdx.y) --------
__global__ __launch_bounds__(256) void hist3(
    const int* __restrict__ d0, const int* __restrict__ d1,
    const int* __restrict__ d2, int* __restrict__ deg) {
  int r = blockIdx.y;
  int e = blockIdx.x * 256 + threadIdx.x;
  if (e >= NE) return;
  const int* d = (r == 0) ? d0 : (r == 1) ? d1 : d2;
  atomicAdd(&deg[r * NT + d[e]], 1);
}

// block partial sums: bsum[r][b] = sum of deg[r][b*256 .. b*256+255]
__global__ __launch_bounds__(256) void scan_s1(const int* __restrict__ deg,
                                               int* __restrict__ bsum) {
  __shared__ int buf[256];
  int r = blockIdx.y, b = blockIdx.x, t = threadIdx.x;
  int idx = b * 256 + t;
  buf[t] = (idx < NT) ? deg[r * NT + idx] : 0;
  __syncthreads();
  for (int s = 128; s > 0; s >>= 1) {
    if (t < s) buf[t] += buf[t + s];
    __syncthreads();
  }
  if (t == 0) bsum[r * NBLK + b] = buf[0];
}

// exclusive scan of the 196 block sums per relation; writes off[NT] totals
__global__ __launch_bounds__(256) void scan_s2(
    const int* __restrict__ bsum, int* __restrict__ boff,
    int* __restrict__ offs /* 3 x (NT+1), stride NT+1 */) {
  __shared__ int buf[256];
  int t = threadIdx.x;
  for (int r = 0; r < 3; r++) {
    int v = (t < NBLK) ? bsum[r * NBLK + t] : 0;
    buf[t] = v;
    __syncthreads();
    for (int s = 1; s < 256; s <<= 1) {
      int u = (t >= s) ? buf[t - s] : 0;
      __syncthreads();
      buf[t] += u;
      __syncthreads();
    }
    if (t < NBLK) boff[r * NBLK + t] = buf[t] - v;
    if (t == 255) offs[(size_t)r * (NT + 1) + NT] = buf[255];
    __syncthreads();
  }
}

// local exclusive scan + block offset; writes off AND cursor copy
__global__ __launch_bounds__(256) void scan_s3(
    const int* __restrict__ deg, const int* __restrict__ boff,
    int* __restrict__ offs, int* __restrict__ cursor) {
  __shared__ int buf[256];
  int r = blockIdx.y, b = blockIdx.x, t = threadIdx.x;
  int idx = b * 256 + t;
  int v = (idx < NT) ? deg[r * NT + idx] : 0;
  buf[t] = v;
  __syncthreads();
  for (int s = 1; s < 256; s <<= 1) {
    int u = (t >= s) ? buf[t - s] : 0;
    __syncthreads();
    buf[t] += u;
    __syncthreads();
  }
  int o = boff[r * NBLK + b] + buf[t] - v;
  if (idx < NT) {
    offs[(size_t)r * (NT + 1) + idx] = o;
    cursor[r * NT + idx] = o;
  }
}

// scatter pre-gathered src node ids into CSR order
__global__ __launch_bounds__(256) void fill3(
    const int* __restrict__ d0, const int* __restrict__ d1,
    const int* __restrict__ d2, const int* __restrict__ s0,
    const int* __restrict__ s1, const int* __restrict__ s2,
    int* __restrict__ cursor, int* __restrict__ csrc) {
  int r = blockIdx.y;
  int e = blockIdx.x * 256 + threadIdx.x;
  if (e >= NE) return;
  const int* d = (r == 0) ? d0 : (r == 1) ? d1 : d2;
  const int* s = (r == 0) ? s0 : (r == 1) ? s1 : s2;
  int p = atomicAdd(&cursor[r * NT + d[e]], 1);
  csrc[(size_t)r * NE + p] = s[e];
}

// -------- MFMA GEMM: C[m,n] = sum_k A[m,k]*Bt[n,k] + bias[n]; N=256 --------
__global__ __launch_bounds__(256) void gemm_mfma(
    const bf16* __restrict__ A, const bf16* __restrict__ Bt,
    const float* __restrict__ bias, bf16* __restrict__ Cout, int M, int K) {
  __shared__ short Als[2][BM * BK];
  __shared__ short Bls[2][BN * BK];
  int bn = blockIdx.x, bm = blockIdx.y;
  int t = threadIdx.x;
  int lane = t & 63;
  int wid = t >> 6;
  int wm = wid >> 1, wn = wid & 1;
  int row0 = bm * BM, col0 = bn * BN;

  f4v acc[4][4] = {};

  const bf16* Abase = A + (size_t)row0 * K;
  const bf16* Bbase = Bt + (size_t)col0 * K;
  int wbase = (t & ~63);

  auto stage = [&](int buf, int ks) {
    int kofs = ks * BK;
    #pragma unroll
    for (int j = 0; j < 2; j++) {
      int slot = j * 256 + t;
      int r = slot >> 2;
      int k0 = (slot & 3) * 8;
      gload_lds16(Abase + (size_t)r * K + kofs + k0,
                  &Als[buf][(j * 256 + wbase) * 8]);
    }
    #pragma unroll
    for (int j = 0; j < 2; j++) {
      int slot = j * 256 + t;
      int r = slot >> 2;
      int k0 = (slot & 3) * 8;
      gload_lds16(Bbase + (size_t)r * K + kofs + k0,
                  &Bls[buf][(j * 256 + wbase) * 8]);
    }
  };

  int nk = K / BK;
  int cur = 0;
  stage(0, 0);
  __syncthreads();

  for (int ks = 0; ks < nk; ks++) {
    if (ks + 1 < nk) stage(cur ^ 1, ks + 1);
    int kq = (lane >> 4) * 8;
    int rr = lane & 15;
    s8v af[4], bfv[4];
    #pragma unroll
    for (int mi = 0; mi < 4; mi++)
      af[mi] = *(const s8v*)&Als[cur][(wm * 64 + mi * 16 + rr) * BK + kq];
    #pragma unroll
    for (int ni = 0; ni < 4; ni++)
      bfv[ni] = *(const s8v*)&Bls[cur][(wn * 64 + ni * 16 + rr) * BK + kq];
    #pragma unroll
    for (int mi = 0; mi < 4; mi++)
      #pragma unroll
      for (int ni = 0; ni < 4; ni++)
        acc[mi][ni] = __builtin_amdgcn_mfma_f32_16x16x32_bf16(
            af[mi], bfv[ni], acc[mi][ni], 0, 0, 0);
    __syncthreads();
    cur ^= 1;
  }

  #pragma unroll
  for (int mi = 0; mi < 4; mi++) {
    int row = row0 + wm * 64 + mi * 16 + (lane >> 4) * 4;
    #pragma unroll
    for (int ni = 0; ni < 4; ni++) {
      int col = col0 + wn * 64 + ni * 16 + (lane & 15);
      float bv = bias[col];
      #pragma unroll
      for (int r = 0; r < 4; r++) {
        if (row + r < M)
          Cout[(size_t)(row + r) * CC + col] = __float2bfloat16(acc[mi][ni][r] + bv);
      }
    }
  }
}

// -------- fused per-dst-node GATv2 (single-pass online softmax) --------
// wave per dst node. mode 0: write acc (f32). mode 1: acc+=, *scale, relu ->
// bf16 hnew (+f32 outf). mode 2: relu -> bf16 hnew (+f32 outf), no acc.
__global__ __launch_bounds__(256) void node_gat_f(
    const int* __restrict__ offs, const int* __restrict__ csrc,
    const bf16* __restrict__ fs, const bf16* __restrict__ fd,
    const float* __restrict__ attn, float* __restrict__ acc,
    bf16* __restrict__ hnew, float* __restrict__ outf,
    float scale, int n_dst, int mode) {
  int wave = blockIdx.x * 4 + (threadIdx.x >> 6);
  if (wave >= n_dst) return;
  int lane = threadIdx.x & 63;
  int h = lane >> 3;
  int off = h * DD + (lane & 7) * 4;

  ushort4 ud = *(const ushort4*)((const unsigned short*)fd + (size_t)wave * CC + off);
  float d0 = bu2f(ud.x), d1 = bu2f(ud.y), d2 = bu2f(ud.z), d3 = bu2f(ud.w);
  float4 at = *(const float4*)(attn + off);

  int e0 = offs[wave], e1 = offs[wave + 1];

  float m = -1e30f, den = 0.f;
  float a0 = 0.f, a1 = 0.f, a2 = 0.f, a3 = 0.f;
  for (int e = e0; e < e1; ++e) {
    int s = csrc[e];
    ushort4 us = *(const ushort4*)((const unsigned short*)fs + (size_t)s * CC + off);
    float f0 = bu2f(us.x), f1 = bu2f(us.y), f2 = bu2f(us.z), f3 = bu2f(us.w);
    float t0 = f0 + d0; t0 = t0 > 0.f ? t0 : 0.2f * t0;
    float t1 = f1 + d1; t1 = t1 > 0.f ? t1 : 0.2f * t1;
    float t2 = f2 + d2; t2 = t2 > 0.f ? t2 : 0.2f * t2;
    float t3 = f3 + d3; t3 = t3 > 0.f ? t3 : 0.2f * t3;
    float lg = t0 * at.x + t1 * at.y + t2 * at.z + t3 * at.w;
    lg += __shfl_xor(lg, 1);
    lg += __shfl_xor(lg, 2);
    lg += __shfl_xor(lg, 4);
    if (lg > m) {
      float c = __expf(m - lg);
      den *= c; a0 *= c; a1 *= c; a2 *= c; a3 *= c;
      m = lg;
    }
    float ex = __expf(lg - m);
    den += ex;
    a0 += ex * f0; a1 += ex * f1; a2 += ex * f2; a3 += ex * f3;
  }
  float inv = (den > 0.f) ? 1.f / den : 0.f;
  a0 *= inv; a1 *= inv; a2 *= inv; a3 *= inv;

  size_t base = (size_t)wave * CC + off;
  if (mode == 0) {
    *(float4*)(acc + base) = make_float4(a0, a1, a2, a3);
  } else {
    if (mode == 1) {
      float4 p = *(const float4*)(acc + base);
      a0 += p.x; a1 += p.y; a2 += p.z; a3 += p.w;
    }
    a0 *= scale; a1 *= scale; a2 *= scale; a3 *= scale;
    a0 = a0 > 0.f ? a0 : 0.f;
    a1 = a1 > 0.f ? a1 : 0.f;
    a2 = a2 > 0.f ? a2 : 0.f;
    a3 = a3 > 0.f ? a3 : 0.f;
    ushort4 o = make_ushort4(f2bu(a0), f2bu(a1), f2bu(a2), f2bu(a3));
    *(ushort4*)((unsigned short*)hnew + base) = o;
    if (outf) *(float4*)(outf + base) = make_float4(a0, a1, a2, a3);
  }
}

extern "C" void kernel_launch(void* const* d_in, const int* in_sizes, int n_in,
                              void* d_out, int out_size, void* d_ws, size_t ws_size,
                              hipStream_t stream) {
  const float* x_tile = (const float*)d_in[0];
  const float* x_poi  = (const float*)d_in[1];
  const int* src_road = (const int*)d_in[2];
  const int* dst_road = (const int*)d_in[3];
  const int* src_tb   = (const int*)d_in[4];
  const int* dst_tb   = (const int*)d_in[5];
  const int* src_ct   = (const int*)d_in[6];
  const int* dst_ct   = (const int*)d_in[7];
  const float* Wsrc[3] = {(const float*)d_in[8],  (const float*)d_in[13], (const float*)d_in[18]};
  const float* bsrc[3] = {(const float*)d_in[9],  (const float*)d_in[14], (const float*)d_in[19]};
  const float* Wdst[3] = {(const float*)d_in[10], (const float*)d_in[15], (const float*)d_in[20]};
  const float* bdst[3] = {(const float*)d_in[11], (const float*)d_in[16], (const float*)d_in[21]};
  const float* attn[3] = {(const float*)d_in[12], (const float*)d_in[17], (const float*)d_in[22]};

  // workspace (~209 MB):
  // tacc: NT*CC f32 | ht2/hp2: 4 x NT*CC bf16 | fs,fd: 2 x NT*CC bf16
  // offs: 3*(NT+1) | deg/cursor: 3*NT | csrc: 3*NE | bsum/boff: 2*3*NBLK | Wt
  float* tacc = (float*)d_ws;
  bf16* hbuf = (bf16*)(tacc + (size_t)NT * CC);
  bf16* ht2[2] = {hbuf, hbuf + (size_t)NT * CC};
  bf16* hp2[2] = {hbuf + 2 * (size_t)NT * CC, hbuf + 3 * (size_t)NT * CC};
  bf16* fs = hbuf + 4 * (size_t)NT * CC;
  bf16* fd = fs + (size_t)NT * CC;
  int* offs   = (int*)(fd + (size_t)NT * CC);   // 3 x (NT+1)
  int* deg    = offs + 3 * (NT + 1);            // 3 x NT (also cursor)
  int* csrc   = deg + 3 * NT;                   // 3 x NE
  int* bsum   = csrc + (size_t)3 * NE;          // 3 x NBLK
  int* boff   = bsum + 3 * NBLK;                // 3 x NBLK
  uintptr_t wp = ((uintptr_t)(boff + 3 * NBLK) + 63) & ~(uintptr_t)63;
  bf16* wsrc_t[3], *wdst_t[3];
  {
    bf16* w = (bf16*)wp;
    for (int l = 0; l < 3; l++) {
      int K = (l == 0) ? 128 : 256;
      wsrc_t[l] = w; w += (size_t)3 * 256 * K;
      wdst_t[l] = w; w += (size_t)3 * 256 * K;
    }
  }

  // convert f32 inputs to bf16 node states (buffer 0)
  cvt_f2b<<<(NT * 128 + 255) / 256, 256, 0, stream>>>(x_tile, ht2[0], NT * 128);
  cvt_f2b<<<(NP * 128 + 255) / 256, 256, 0, stream>>>(x_poi, hp2[0], NP * 128);

  // convert + transpose weights to bf16
  for (int l = 0; l < 3; l++) {
    int K = (l == 0) ? 128 : 256;
    int tot = 3 * 256 * K;
    wt_cvt<<<(tot + 255) / 256, 256, 0, stream>>>(Wsrc[l], wsrc_t[l], K);
    wt_cvt<<<(tot + 255) / 256, 256, 0, stream>>>(Wdst[l], wdst_t[l], K);
  }

  // build CSR for the 3 relations (batched, parallel scan)
  zero_i<<<(3 * NT + 255) / 256, 256, 0, stream>>>(deg, 3 * NT);
  {
    dim3 ge((NE + 255) / 256, 3);
    hist3<<<ge, 256, 0, stream>>>(dst_road, dst_tb, dst_ct, deg);
    dim3 gn(NBLK, 3);
    scan_s1<<<gn, 256, 0, stream>>>(deg, bsum);
    scan_s2<<<1, 256, 0, stream>>>(bsum, boff, offs);
    scan_s3<<<gn, 256, 0, stream>>>(deg, boff, offs, deg /*cursor*/);
    fill3<<<ge, 256, 0, stream>>>(dst_road, dst_tb, dst_ct,
                                  src_road, src_tb, src_ct, deg, csrc);
  }

  int cb = 0;
  for (int l = 0; l < 3; l++) {
    int K = (l == 0) ? 128 : 256;
    bf16* ht_c = ht2[cb], *hp_c = hp2[cb];
    bf16* ht_n = ht2[cb ^ 1], *hp_n = hp2[cb ^ 1];
    float st = (l == 1) ? 0.5f : 1.0f;
    float* outT = (l == 2) ? (float*)d_out : nullptr;
    float* outP = (l == 2) ? ((float*)d_out + (size_t)NT * CC) : nullptr;

    struct Rel {
      const bf16* hs; const bf16* hd;
      bf16* hnew; float* outf; float scale; int mode;
    };
    Rel rels[3] = {
      {ht_c, ht_c, nullptr, nullptr, 1.0f, 0},
      {hp_c, ht_c, ht_n,    outT,    st,   1},
      {ht_c, hp_c, hp_n,    outP,    1.0f, 2},
    };

    for (int r = 0; r < 3; r++) {
      const bf16* Wst = wsrc_t[l] + (size_t)r * 256 * K;
      const bf16* Wdt = wdst_t[l] + (size_t)r * 256 * K;
      const float* bs = bsrc[l] + (size_t)r * CC;
      const float* bd = bdst[l] + (size_t)r * CC;
      const float* at = attn[l] + (size_t)r * CC;

      dim3 gs(2, (NT + BM - 1) / BM);
      gemm_mfma<<<gs, 256, 0, stream>>>(rels[r].hs, Wst, bs, fs, NT, K);
      gemm_mfma<<<gs, 256, 0, stream>>>(rels[r].hd, Wdt, bd, fd, NT, K);

      node_gat_f<<<(NT + 3) / 4, 256, 0, stream>>>(
          offs + (size_t)r * (NT + 1), csrc + (size_t)r * NE, fs, fd, at,
          tacc, rels[r].hnew, rels[r].outf, rels[r].scale, NT, rels[r].mode);
    }
    cb ^= 1;
  }
}

// Round 7
// 748.793 us; speedup vs baseline: 10.6946x; 1.2415x over previous
//
#include <hip/hip_runtime.h>
#include <hip/hip_bf16.h>

typedef __hip_bfloat16 bf16;

#define NT 50000
#define NP 50000
#define NE 200000
#define HH 8
#define DD 32
#define CC 256   // H*D
#define NBLK 196 // ceil(NT/256)

#define BM 128
#define BK 32

typedef short s8v __attribute__((ext_vector_type(8)));   // 8 bf16 (4 VGPRs)
typedef float f4v __attribute__((ext_vector_type(4)));   // 4 f32 acc

__device__ __forceinline__ float bu2f(unsigned short u) {
  return __uint_as_float(((unsigned)u) << 16);
}
__device__ __forceinline__ unsigned short f2bu(float x) {
  bf16 b = __float2bfloat16(x);
  return *(unsigned short*)&b;
}

__device__ __forceinline__ void gload_lds16(const void* g, void* l) {
  __builtin_amdgcn_global_load_lds(
      (const __attribute__((address_space(1))) void*)g,
      (__attribute__((address_space(3))) void*)l, 16, 0, 0);
}

// -------- input convert --------
__global__ __launch_bounds__(256) void cvt_f2b(const float* __restrict__ in,
                                               bf16* __restrict__ out, int n) {
  int i = blockIdx.x * 256 + threadIdx.x;
  if (i < n) out[i] = __float2bfloat16(in[i]);
}

// -------- weight prep: all layers/blocks in one dispatch --------
// W1cat[l] (1024 x K) rows: [Ws rel0 | Wd rel0 | Wd rel1 | Ws rel2]
// W2cat[l] ( 512 x K) rows: [Ws rel1 | Wd rel2]
struct WtArgs {
  const float* Ws[3]; const float* Wd[3];
  bf16* W1[3]; bf16* W2[3];
};
__global__ __launch_bounds__(256) void wt_cvt_all(WtArgs a) {
  int l = blockIdx.z, y = blockIdx.y;
  int K = (l == 0) ? 128 : 256;
  int idx = blockIdx.x * 256 + threadIdx.x;
  if (idx >= 256 * K) return;
  int n = idx / K, k = idx - n * K;
  const float* W; bf16* D; int dn;
  if (y == 0)      { W = a.Ws[l];                       D = a.W1[l]; dn = n; }
  else if (y == 1) { W = a.Wd[l];                       D = a.W1[l]; dn = n + 256; }
  else if (y == 2) { W = a.Wd[l] + (size_t)1 * K * 256; D = a.W1[l]; dn = n + 512; }
  else if (y == 3) { W = a.Ws[l] + (size_t)2 * K * 256; D = a.W1[l]; dn = n + 768; }
  else if (y == 4) { W = a.Ws[l] + (size_t)1 * K * 256; D = a.W2[l]; dn = n; }
  else             { W = a.Wd[l] + (size_t)2 * K * 256; D = a.W2[l]; dn = n + 256; }
  D[(size_t)dn * K + k] = __float2bfloat16(W[(size_t)k * 256 + n]);
}

struct BiArgs {
  const float* bs[3]; const float* bd[3];
  float* b1; float* b2;  // b1: 3*1024, b2: 3*512
};
__global__ __launch_bounds__(256) void bias_cat(BiArgs a) {
  int l = blockIdx.y, y = blockIdx.x;
  int n = threadIdx.x;
  float v;
  if (y == 0)      v = a.bs[l][n];
  else if (y == 1) v = a.bd[l][n];
  else if (y == 2) v = a.bd[l][256 + n];
  else if (y == 3) v = a.bs[l][512 + n];
  else if (y == 4) v = a.bs[l][256 + n];
  else             v = a.bd[l][512 + n];
  if (y < 4) a.b1[l * 1024 + y * 256 + n] = v;
  else       a.b2[l * 512 + (y - 4) * 256 + n] = v;
}

__global__ __launch_bounds__(256) void zero_i(int* __restrict__ p, int n) {
  int i = blockIdx.x * 256 + threadIdx.x;
  if (i < n) p[i] = 0;
}

// -------- CSR build (batched over 3 relations via blockIdx.y) --------
__global__ __launch_bounds__(256) void hist3(
    const int* __restrict__ d0, const int* __restrict__ d1,
    const int* __restrict__ d2, int* __restrict__ deg) {
  int r = blockIdx.y;
  int e = blockIdx.x * 256 + threadIdx.x;
  if (e >= NE) return;
  const int* d = (r == 0) ? d0 : (r == 1) ? d1 : d2;
  atomicAdd(&deg[r * NT + d[e]], 1);
}

__global__ __launch_bounds__(256) void scan_s1(const int* __restrict__ deg,
                                               int* __restrict__ bsum) {
  __shared__ int buf[256];
  int r = blockIdx.y, b = blockIdx.x, t = threadIdx.x;
  int idx = b * 256 + t;
  buf[t] = (idx < NT) ? deg[r * NT + idx] : 0;
  __syncthreads();
  for (int s = 128; s > 0; s >>= 1) {
    if (t < s) buf[t] += buf[t + s];
    __syncthreads();
  }
  if (t == 0) bsum[r * NBLK + b] = buf[0];
}

__global__ __launch_bounds__(256) void scan_s2(
    const int* __restrict__ bsum, int* __restrict__ boff,
    int* __restrict__ offs) {
  __shared__ int buf[256];
  int t = threadIdx.x;
  for (int r = 0; r < 3; r++) {
    int v = (t < NBLK) ? bsum[r * NBLK + t] : 0;
    buf[t] = v;
    __syncthreads();
    for (int s = 1; s < 256; s <<= 1) {
      int u = (t >= s) ? buf[t - s] : 0;
      __syncthreads();
      buf[t] += u;
      __syncthreads();
    }
    if (t < NBLK) boff[r * NBLK + t] = buf[t] - v;
    if (t == 255) offs[(size_t)r * (NT + 1) + NT] = buf[255];
    __syncthreads();
  }
}

__global__ __launch_bounds__(256) void scan_s3(
    const int* __restrict__ deg, const int* __restrict__ boff,
    int* __restrict__ offs, int* __restrict__ cursor) {
  __shared__ int buf[256];
  int r = blockIdx.y, b = blockIdx.x, t = threadIdx.x;
  int idx = b * 256 + t;
  int v = (idx < NT) ? deg[r * NT + idx] : 0;
  buf[t] = v;
  __syncthreads();
  for (int s = 1; s < 256; s <<= 1) {
    int u = (t >= s) ? buf[t - s] : 0;
    __syncthreads();
    buf[t] += u;
    __syncthreads();
  }
  int o = boff[r * NBLK + b] + buf[t] - v;
  if (idx < NT) {
    offs[(size_t)r * (NT + 1) + idx] = o;
    cursor[r * NT + idx] = o;
  }
}

__global__ __launch_bounds__(256) void fill3(
    const int* __restrict__ d0, const int* __restrict__ d1,
    const int* __restrict__ d2, const int* __restrict__ s0,
    const int* __restrict__ s1, const int* __restrict__ s2,
    int* __restrict__ cursor, int* __restrict__ csrc) {
  int r = blockIdx.y;
  int e = blockIdx.x * 256 + threadIdx.x;
  if (e >= NE) return;
  const int* d = (r == 0) ? d0 : (r == 1) ? d1 : d2;
  const int* s = (r == 0) ? s0 : (r == 1) ? s1 : s2;
  int p = atomicAdd(&cursor[r * NT + d[e]], 1);
  csrc[(size_t)r * NE + p] = s[e];
}

// -------- MFMA GEMM: C[m,n] = sum_k A[m,k]*Bt[n,k] + bias[n] --------
// A bf16 (M x K), Bt bf16 (Ncols x K), out bf16 (M x Ncols)
__global__ __launch_bounds__(256) void gemm_mfma(
    const bf16* __restrict__ A, const bf16* __restrict__ Bt,
    const float* __restrict__ bias, bf16* __restrict__ Cout,
    int M, int K, int Ncols) {
  __shared__ short Als[2][BM * BK];
  __shared__ short Bls[2][BM * BK];
  int bn = blockIdx.x, bm = blockIdx.y;
  int t = threadIdx.x;
  int lane = t & 63;
  int wid = t >> 6;
  int wm = wid >> 1, wn = wid & 1;
  int row0 = bm * BM, col0 = bn * BM;

  f4v acc[4][4] = {};

  const bf16* Abase = A + (size_t)row0 * K;
  const bf16* Bbase = Bt + (size_t)col0 * K;
  int wbase = (t & ~63);

  auto stage = [&](int buf, int ks) {
    int kofs = ks * BK;
    #pragma unroll
    for (int j = 0; j < 2; j++) {
      int slot = j * 256 + t;
      int r = slot >> 2;
      int k0 = (slot & 3) * 8;
      gload_lds16(Abase + (size_t)r * K + kofs + k0,
                  &Als[buf][(j * 256 + wbase) * 8]);
    }
    #pragma unroll
    for (int j = 0; j < 2; j++) {
      int slot = j * 256 + t;
      int r = slot >> 2;
      int k0 = (slot & 3) * 8;
      gload_lds16(Bbase + (size_t)r * K + kofs + k0,
                  &Bls[buf][(j * 256 + wbase) * 8]);
    }
  };

  int nk = K / BK;
  int cur = 0;
  stage(0, 0);
  __syncthreads();

  for (int ks = 0; ks < nk; ks++) {
    if (ks + 1 < nk) stage(cur ^ 1, ks + 1);
    int kq = (lane >> 4) * 8;
    int rr = lane & 15;
    s8v af[4], bfv[4];
    #pragma unroll
    for (int mi = 0; mi < 4; mi++)
      af[mi] = *(const s8v*)&Als[cur][(wm * 64 + mi * 16 + rr) * BK + kq];
    #pragma unroll
    for (int ni = 0; ni < 4; ni++)
      bfv[ni] = *(const s8v*)&Bls[cur][(wn * 64 + ni * 16 + rr) * BK + kq];
    #pragma unroll
    for (int mi = 0; mi < 4; mi++)
      #pragma unroll
      for (int ni = 0; ni < 4; ni++)
        acc[mi][ni] = __builtin_amdgcn_mfma_f32_16x16x32_bf16(
            af[mi], bfv[ni], acc[mi][ni], 0, 0, 0);
    __syncthreads();
    cur ^= 1;
  }

  #pragma unroll
  for (int mi = 0; mi < 4; mi++) {
    int row = row0 + wm * 64 + mi * 16 + (lane >> 4) * 4;
    #pragma unroll
    for (int ni = 0; ni < 4; ni++) {
      int col = col0 + wn * 64 + ni * 16 + (lane & 15);
      float bv = bias[col];
      #pragma unroll
      for (int r = 0; r < 4; r++) {
        if (row + r < M)
          Cout[(size_t)(row + r) * Ncols + col] =
              __float2bfloat16(acc[mi][ni][r] + bv);
      }
    }
  }
}

// -------- per-relation online-softmax gather (helper) --------
__device__ __forceinline__ float4 gat_pass(
    int e0, int e1, const int* __restrict__ csrc,
    const unsigned short* __restrict__ fsoff, size_t fstride,
    float d0, float d1, float d2, float d3, float4 at) {
  float m = -1e30f, den = 0.f;
  float a0 = 0.f, a1 = 0.f, a2 = 0.f, a3 = 0.f;
  for (int e = e0; e < e1; ++e) {
    int s = csrc[e];
    ushort4 us = *(const ushort4*)(fsoff + (size_t)s * fstride);
    float f0 = bu2f(us.x), f1 = bu2f(us.y), f2 = bu2f(us.z), f3 = bu2f(us.w);
    float t0 = f0 + d0; t0 = t0 > 0.f ? t0 : 0.2f * t0;
    float t1 = f1 + d1; t1 = t1 > 0.f ? t1 : 0.2f * t1;
    float t2 = f2 + d2; t2 = t2 > 0.f ? t2 : 0.2f * t2;
    float t3 = f3 + d3; t3 = t3 > 0.f ? t3 : 0.2f * t3;
    float lg = t0 * at.x + t1 * at.y + t2 * at.z + t3 * at.w;
    lg += __shfl_xor(lg, 1);
    lg += __shfl_xor(lg, 2);
    lg += __shfl_xor(lg, 4);
    if (lg > m) {
      float c = __expf(m - lg);
      den *= c; a0 *= c; a1 *= c; a2 *= c; a3 *= c;
      m = lg;
    }
    float ex = __expf(lg - m);
    den += ex;
    a0 += ex * f0; a1 += ex * f1; a2 += ex * f2; a3 += ex * f3;
  }
  float inv = (den > 0.f) ? 1.f / den : 0.f;
  return make_float4(a0 * inv, a1 * inv, a2 * inv, a3 * inv);
}

// -------- tile nodes: road (F1) + tb (F2) fused, scale+ReLU epilogue --------
// F1 cols: [fs_road | fd_road | fd_tb | fs_ct], F2 cols: [fs_tb | fd_ct]
__global__ __launch_bounds__(256) void node_gat_tile(
    const int* __restrict__ offsA, const int* __restrict__ csA,
    const int* __restrict__ offsB, const int* __restrict__ csB,
    const bf16* __restrict__ F1, const bf16* __restrict__ F2,
    const float* __restrict__ attnL, float scale,
    bf16* __restrict__ hnew, float* __restrict__ outf) {
  int wave = blockIdx.x * 4 + (threadIdx.x >> 6);
  if (wave >= NT) return;
  int lane = threadIdx.x & 63;
  int off = (lane >> 3) * DD + (lane & 7) * 4;
  const unsigned short* F1u = (const unsigned short*)F1;
  const unsigned short* F2u = (const unsigned short*)F2;

  ushort4 udA = *(const ushort4*)(F1u + (size_t)wave * 1024 + 256 + off);
  float4 atA = *(const float4*)(attnL + off);
  float4 ra = gat_pass(offsA[wave], offsA[wave + 1], csA, F1u + off, 1024,
                       bu2f(udA.x), bu2f(udA.y), bu2f(udA.z), bu2f(udA.w), atA);

  ushort4 udB = *(const ushort4*)(F1u + (size_t)wave * 1024 + 512 + off);
  float4 atB = *(const float4*)(attnL + 256 + off);
  float4 rb = gat_pass(offsB[wave], offsB[wave + 1], csB, F2u + off, 512,
                       bu2f(udB.x), bu2f(udB.y), bu2f(udB.z), bu2f(udB.w), atB);

  float v0 = (ra.x + rb.x) * scale; v0 = v0 > 0.f ? v0 : 0.f;
  float v1 = (ra.y + rb.y) * scale; v1 = v1 > 0.f ? v1 : 0.f;
  float v2 = (ra.z + rb.z) * scale; v2 = v2 > 0.f ? v2 : 0.f;
  float v3 = (ra.w + rb.w) * scale; v3 = v3 > 0.f ? v3 : 0.f;

  size_t base = (size_t)wave * CC + off;
  *(ushort4*)((unsigned short*)hnew + base) =
      make_ushort4(f2bu(v0), f2bu(v1), f2bu(v2), f2bu(v3));
  if (outf) *(float4*)(outf + base) = make_float4(v0, v1, v2, v3);
}

// -------- poi nodes: ct relation (fs from F1 block 3, fd from F2 block 1) ----
__global__ __launch_bounds__(256) void node_gat_poi(
    const int* __restrict__ offsC, const int* __restrict__ csC,
    const bf16* __restrict__ F1, const bf16* __restrict__ F2,
    const float* __restrict__ attnL,
    bf16* __restrict__ hnew, float* __restrict__ outf) {
  int wave = blockIdx.x * 4 + (threadIdx.x >> 6);
  if (wave >= NP) return;
  int lane = threadIdx.x & 63;
  int off = (lane >> 3) * DD + (lane & 7) * 4;
  const unsigned short* F1u = (const unsigned short*)F1;
  const unsigned short* F2u = (const unsigned short*)F2;

  ushort4 ud = *(const ushort4*)(F2u + (size_t)wave * 512 + 256 + off);
  float4 at = *(const float4*)(attnL + 512 + off);
  float4 r = gat_pass(offsC[wave], offsC[wave + 1], csC, F1u + 768 + off, 1024,
                      bu2f(ud.x), bu2f(ud.y), bu2f(ud.z), bu2f(ud.w), at);

  float v0 = r.x > 0.f ? r.x : 0.f;
  float v1 = r.y > 0.f ? r.y : 0.f;
  float v2 = r.z > 0.f ? r.z : 0.f;
  float v3 = r.w > 0.f ? r.w : 0.f;

  size_t base = (size_t)wave * CC + off;
  *(ushort4*)((unsigned short*)hnew + base) =
      make_ushort4(f2bu(v0), f2bu(v1), f2bu(v2), f2bu(v3));
  if (outf) *(float4*)(outf + base) = make_float4(v0, v1, v2, v3);
}

extern "C" void kernel_launch(void* const* d_in, const int* in_sizes, int n_in,
                              void* d_out, int out_size, void* d_ws, size_t ws_size,
                              hipStream_t stream) {
  const float* x_tile = (const float*)d_in[0];
  const float* x_poi  = (const float*)d_in[1];
  const int* src_road = (const int*)d_in[2];
  const int* dst_road = (const int*)d_in[3];
  const int* src_tb   = (const int*)d_in[4];
  const int* dst_tb   = (const int*)d_in[5];
  const int* src_ct   = (const int*)d_in[6];
  const int* dst_ct   = (const int*)d_in[7];
  const float* Wsrc[3] = {(const float*)d_in[8],  (const float*)d_in[13], (const float*)d_in[18]};
  const float* bsrc[3] = {(const float*)d_in[9],  (const float*)d_in[14], (const float*)d_in[19]};
  const float* Wdst[3] = {(const float*)d_in[10], (const float*)d_in[15], (const float*)d_in[20]};
  const float* bdst[3] = {(const float*)d_in[11], (const float*)d_in[16], (const float*)d_in[21]};
  const float* attn[3] = {(const float*)d_in[12], (const float*)d_in[17], (const float*)d_in[22]};

  // workspace (~262 MB): ht2/hp2 4x25.6 | F1 102.4 | F2 51.2 | CSR ~3.6 | W ~2
  bf16* hbuf = (bf16*)d_ws;
  bf16* ht2[2] = {hbuf, hbuf + (size_t)NT * CC};
  bf16* hp2[2] = {hbuf + 2 * (size_t)NT * CC, hbuf + 3 * (size_t)NT * CC};
  bf16* F1 = hbuf + 4 * (size_t)NT * CC;
  bf16* F2 = F1 + (size_t)NT * 1024;
  int* offs = (int*)(F2 + (size_t)NT * 512);   // 3 x (NT+1)
  int* deg  = offs + 3 * (NT + 1);             // 3 x NT (reused as cursor)
  int* csrc = deg + 3 * NT;                    // 3 x NE
  int* bsum = csrc + (size_t)3 * NE;
  int* boff = bsum + 3 * NBLK;
  uintptr_t wp = ((uintptr_t)(boff + 3 * NBLK) + 63) & ~(uintptr_t)63;
  bf16* W1c[3], *W2c[3];
  {
    bf16* w = (bf16*)wp;
    for (int l = 0; l < 3; l++) {
      int K = (l == 0) ? 128 : 256;
      W1c[l] = w; w += (size_t)1024 * K;
      W2c[l] = w; w += (size_t)512 * K;
    }
    wp = (uintptr_t)w;
  }
  float* b1 = (float*)((wp + 63) & ~(uintptr_t)63);   // 3 x 1024
  float* b2 = b1 + 3 * 1024;                          // 3 x 512

  // input converts
  cvt_f2b<<<(NT * 128 + 255) / 256, 256, 0, stream>>>(x_tile, ht2[0], NT * 128);
  cvt_f2b<<<(NP * 128 + 255) / 256, 256, 0, stream>>>(x_poi, hp2[0], NP * 128);

  // weight + bias prep (one dispatch each)
  {
    WtArgs wa;
    BiArgs ba;
    for (int l = 0; l < 3; l++) {
      wa.Ws[l] = Wsrc[l]; wa.Wd[l] = Wdst[l];
      wa.W1[l] = W1c[l];  wa.W2[l] = W2c[l];
      ba.bs[l] = bsrc[l]; ba.bd[l] = bdst[l];
    }
    ba.b1 = b1; ba.b2 = b2;
    dim3 gw(256, 6, 3);
    wt_cvt_all<<<gw, 256, 0, stream>>>(wa);
    dim3 gb(6, 3);
    bias_cat<<<gb, 256, 0, stream>>>(ba);
  }

  // CSR build
  zero_i<<<(3 * NT + 255) / 256, 256, 0, stream>>>(deg, 3 * NT);
  {
    dim3 ge((NE + 255) / 256, 3);
    hist3<<<ge, 256, 0, stream>>>(dst_road, dst_tb, dst_ct, deg);
    dim3 gn(NBLK, 3);
    scan_s1<<<gn, 256, 0, stream>>>(deg, bsum);
    scan_s2<<<1, 256, 0, stream>>>(bsum, boff, offs);
    scan_s3<<<gn, 256, 0, stream>>>(deg, boff, offs, deg);
    fill3<<<ge, 256, 0, stream>>>(dst_road, dst_tb, dst_ct,
                                  src_road, src_tb, src_ct, deg, csrc);
  }

  int cb = 0;
  for (int l = 0; l < 3; l++) {
    int K = (l == 0) ? 128 : 256;
    bf16* ht_c = ht2[cb], *hp_c = hp2[cb];
    bf16* ht_n = ht2[cb ^ 1], *hp_n = hp2[cb ^ 1];
    float st = (l == 1) ? 0.5f : 1.0f;
    float* outT = (l == 2) ? (float*)d_out : nullptr;
    float* outP = (l == 2) ? ((float*)d_out + (size_t)NT * CC) : nullptr;

    dim3 g1(8, (NT + BM - 1) / BM);
    gemm_mfma<<<g1, 256, 0, stream>>>(ht_c, W1c[l], b1 + l * 1024, F1, NT, K, 1024);
    dim3 g2(4, (NT + BM - 1) / BM);
    gemm_mfma<<<g2, 256, 0, stream>>>(hp_c, W2c[l], b2 + l * 512, F2, NT, K, 512);

    node_gat_tile<<<(NT + 3) / 4, 256, 0, stream>>>(
        offs, csrc, offs + (NT + 1), csrc + NE, F1, F2, attn[l], st, ht_n, outT);
    node_gat_poi<<<(NP + 3) / 4, 256, 0, stream>>>(
        offs + 2 * (NT + 1), csrc + 2 * (size_t)NE, F1, F2, attn[l], hp_n, outP);

    cb ^= 1;
  }
}

// Round 8
// 706.871 us; speedup vs baseline: 11.3289x; 1.0593x over previous
//
#include <hip/hip_runtime.h>
#include <hip/hip_bf16.h>

typedef __hip_bfloat16 bf16;

#define NT 50000
#define NP 50000
#define NE 200000
#define HH 8
#define DD 32
#define CC 256   // H*D
#define NBLK 196 // ceil(NT/256)

#define BM 128
#define BK 32

typedef short s8v __attribute__((ext_vector_type(8)));   // 8 bf16 (4 VGPRs)
typedef float f4v __attribute__((ext_vector_type(4)));   // 4 f32 acc

__device__ __forceinline__ float bu2f(unsigned short u) {
  return __uint_as_float(((unsigned)u) << 16);
}
__device__ __forceinline__ unsigned short f2bu(float x) {
  bf16 b = __float2bfloat16(x);
  return *(unsigned short*)&b;
}

__device__ __forceinline__ void gload_lds16(const void* g, void* l) {
  __builtin_amdgcn_global_load_lds(
      (const __attribute__((address_space(1))) void*)g,
      (__attribute__((address_space(3))) void*)l, 16, 0, 0);
}

// -------- input convert --------
__global__ __launch_bounds__(256) void cvt_f2b(const float* __restrict__ in,
                                               bf16* __restrict__ out, int n) {
  int i = blockIdx.x * 256 + threadIdx.x;
  if (i < n) out[i] = __float2bfloat16(in[i]);
}

// -------- weight prep --------
// W1cat[l] (1024 x K) rows: [Ws rel0 | Wd rel0 | Wd rel1 | Ws rel2]
// W2cat[l] ( 512 x K) rows: [Ws rel1 | Wd rel2]
struct WtArgs {
  const float* Ws[3]; const float* Wd[3];
  bf16* W1[3]; bf16* W2[3];
};
__global__ __launch_bounds__(256) void wt_cvt_all(WtArgs a) {
  int l = blockIdx.z, y = blockIdx.y;
  int K = (l == 0) ? 128 : 256;
  int idx = blockIdx.x * 256 + threadIdx.x;
  if (idx >= 256 * K) return;
  int n = idx / K, k = idx - n * K;
  const float* W; bf16* D; int dn;
  if (y == 0)      { W = a.Ws[l];                       D = a.W1[l]; dn = n; }
  else if (y == 1) { W = a.Wd[l];                       D = a.W1[l]; dn = n + 256; }
  else if (y == 2) { W = a.Wd[l] + (size_t)1 * K * 256; D = a.W1[l]; dn = n + 512; }
  else if (y == 3) { W = a.Ws[l] + (size_t)2 * K * 256; D = a.W1[l]; dn = n + 768; }
  else if (y == 4) { W = a.Ws[l] + (size_t)1 * K * 256; D = a.W2[l]; dn = n; }
  else             { W = a.Wd[l] + (size_t)2 * K * 256; D = a.W2[l]; dn = n + 256; }
  D[(size_t)dn * K + k] = __float2bfloat16(W[(size_t)k * 256 + n]);
}

struct BiArgs {
  const float* bs[3]; const float* bd[3];
  float* b1; float* b2;  // b1: 3*1024, b2: 3*512
};
__global__ __launch_bounds__(256) void bias_cat(BiArgs a) {
  int l = blockIdx.y, y = blockIdx.x;
  int n = threadIdx.x;
  float v;
  if (y == 0)      v = a.bs[l][n];
  else if (y == 1) v = a.bd[l][n];
  else if (y == 2) v = a.bd[l][256 + n];
  else if (y == 3) v = a.bs[l][512 + n];
  else if (y == 4) v = a.bs[l][256 + n];
  else             v = a.bd[l][512 + n];
  if (y < 4) a.b1[l * 1024 + y * 256 + n] = v;
  else       a.b2[l * 512 + (y - 4) * 256 + n] = v;
}

__global__ __launch_bounds__(256) void zero_i(int* __restrict__ p, int n) {
  int i = blockIdx.x * 256 + threadIdx.x;
  if (i < n) p[i] = 0;
}

// -------- CSR build (batched over 3 relations via blockIdx.y) --------
__global__ __launch_bounds__(256) void hist3(
    const int* __restrict__ d0, const int* __restrict__ d1,
    const int* __restrict__ d2, int* __restrict__ deg) {
  int r = blockIdx.y;
  int e = blockIdx.x * 256 + threadIdx.x;
  if (e >= NE) return;
  const int* d = (r == 0) ? d0 : (r == 1) ? d1 : d2;
  atomicAdd(&deg[r * NT + d[e]], 1);
}

__global__ __launch_bounds__(256) void scan_s1(const int* __restrict__ deg,
                                               int* __restrict__ bsum) {
  __shared__ int buf[256];
  int r = blockIdx.y, b = blockIdx.x, t = threadIdx.x;
  int idx = b * 256 + t;
  buf[t] = (idx < NT) ? deg[r * NT + idx] : 0;
  __syncthreads();
  for (int s = 128; s > 0; s >>= 1) {
    if (t < s) buf[t] += buf[t + s];
    __syncthreads();
  }
  if (t == 0) bsum[r * NBLK + b] = buf[0];
}

__global__ __launch_bounds__(256) void scan_s2(
    const int* __restrict__ bsum, int* __restrict__ boff,
    int* __restrict__ offs) {
  __shared__ int buf[256];
  int t = threadIdx.x;
  for (int r = 0; r < 3; r++) {
    int v = (t < NBLK) ? bsum[r * NBLK + t] : 0;
    buf[t] = v;
    __syncthreads();
    for (int s = 1; s < 256; s <<= 1) {
      int u = (t >= s) ? buf[t - s] : 0;
      __syncthreads();
      buf[t] += u;
      __syncthreads();
    }
    if (t < NBLK) boff[r * NBLK + t] = buf[t] - v;
    if (t == 255) offs[(size_t)r * (NT + 1) + NT] = buf[255];
    __syncthreads();
  }
}

__global__ __launch_bounds__(256) void scan_s3(
    const int* __restrict__ deg, const int* __restrict__ boff,
    int* __restrict__ offs, int* __restrict__ cursor) {
  __shared__ int buf[256];
  int r = blockIdx.y, b = blockIdx.x, t = threadIdx.x;
  int idx = b * 256 + t;
  int v = (idx < NT) ? deg[r * NT + idx] : 0;
  buf[t] = v;
  __syncthreads();
  for (int s = 1; s < 256; s <<= 1) {
    int u = (t >= s) ? buf[t - s] : 0;
    __syncthreads();
    buf[t] += u;
    __syncthreads();
  }
  int o = boff[r * NBLK + b] + buf[t] - v;
  if (idx < NT) {
    offs[(size_t)r * (NT + 1) + idx] = o;
    cursor[r * NT + idx] = o;
  }
}

__global__ __launch_bounds__(256) void fill3(
    const int* __restrict__ d0, const int* __restrict__ d1,
    const int* __restrict__ d2, const int* __restrict__ s0,
    const int* __restrict__ s1, const int* __restrict__ s2,
    int* __restrict__ cursor, int* __restrict__ csrc) {
  int r = blockIdx.y;
  int e = blockIdx.x * 256 + threadIdx.x;
  if (e >= NE) return;
  const int* d = (r == 0) ? d0 : (r == 1) ? d1 : d2;
  const int* s = (r == 0) ? s0 : (r == 1) ? s1 : s2;
  int p = atomicAdd(&cursor[r * NT + d[e]], 1);
  csrc[(size_t)r * NE + p] = s[e];
}

// -------- MFMA GEMM (XCD-chunked 1D grid + LDS XOR swizzle) --------
// A bf16 (M x K), Bt bf16 (Ncols x K), out bf16 (M x Ncols)
// LDS slot s (16B) holds row s>>2, k-chunk ((s&3) ^ ((s>>3)&3)).
__global__ __launch_bounds__(256) void gemm_mfma(
    const bf16* __restrict__ A, const bf16* __restrict__ Bt,
    const float* __restrict__ bias, bf16* __restrict__ Cout,
    int M, int K, int Ncols, int nbn, int q8, int r8) {
  __shared__ short Als[2][BM * BK];
  __shared__ short Bls[2][BM * BK];
  // bijective XCD-chunked remap (m204): hw linear id round-robins XCDs
  int bid = blockIdx.x;
  int xcd = bid & 7, pos = bid >> 3;
  int wgid = (xcd < r8 ? xcd * (q8 + 1) : r8 * (q8 + 1) + (xcd - r8) * q8) + pos;
  int bm = wgid / nbn;
  int bn = wgid - bm * nbn;

  int t = threadIdx.x;
  int lane = t & 63;
  int wid = t >> 6;
  int wm = wid >> 1, wn = wid & 1;
  int row0 = bm * BM, col0 = bn * BM;

  f4v acc[4][4] = {};

  const bf16* Abase = A + (size_t)row0 * K;
  const bf16* Bbase = Bt + (size_t)col0 * K;
  int wbase = (t & ~63);

  auto stage = [&](int buf, int ks) {
    int kofs = ks * BK;
    #pragma unroll
    for (int j = 0; j < 2; j++) {
      int slot = j * 256 + t;
      int r = slot >> 2;
      int c = (slot & 3) ^ ((slot >> 3) & 3);   // inverse swizzle on source
      gload_lds16(Abase + (size_t)r * K + kofs + c * 8,
                  &Als[buf][(j * 256 + wbase) * 8]);
    }
    #pragma unroll
    for (int j = 0; j < 2; j++) {
      int slot = j * 256 + t;
      int r = slot >> 2;
      int c = (slot & 3) ^ ((slot >> 3) & 3);
      gload_lds16(Bbase + (size_t)r * K + kofs + c * 8,
                  &Bls[buf][(j * 256 + wbase) * 8]);
    }
  };

  int nk = K / BK;
  int cur = 0;
  stage(0, 0);
  __syncthreads();

  for (int ks = 0; ks < nk; ks++) {
    if (ks + 1 < nk) stage(cur ^ 1, ks + 1);
    int c = lane >> 4;
    int rr = lane & 15;
    s8v af[4], bfv[4];
    #pragma unroll
    for (int mi = 0; mi < 4; mi++) {
      int R = wm * 64 + mi * 16 + rr;
      af[mi] = *(const s8v*)&Als[cur][(R * 4 + (c ^ ((R >> 1) & 3))) * 8];
    }
    #pragma unroll
    for (int ni = 0; ni < 4; ni++) {
      int R = wn * 64 + ni * 16 + rr;
      bfv[ni] = *(const s8v*)&Bls[cur][(R * 4 + (c ^ ((R >> 1) & 3))) * 8];
    }
    #pragma unroll
    for (int mi = 0; mi < 4; mi++)
      #pragma unroll
      for (int ni = 0; ni < 4; ni++)
        acc[mi][ni] = __builtin_amdgcn_mfma_f32_16x16x32_bf16(
            af[mi], bfv[ni], acc[mi][ni], 0, 0, 0);
    __syncthreads();
    cur ^= 1;
  }

  #pragma unroll
  for (int mi = 0; mi < 4; mi++) {
    int row = row0 + wm * 64 + mi * 16 + (lane >> 4) * 4;
    #pragma unroll
    for (int ni = 0; ni < 4; ni++) {
      int col = col0 + wn * 64 + ni * 16 + (lane & 15);
      float bv = bias[col];
      #pragma unroll
      for (int r = 0; r < 4; r++) {
        if (row + r < M)
          Cout[(size_t)(row + r) * Ncols + col] =
              __float2bfloat16(acc[mi][ni][r] + bv);
      }
    }
  }
}

// -------- per-relation online-softmax gather (helper) --------
__device__ __forceinline__ float4 gat_pass(
    int e0, int e1, const int* __restrict__ csrc,
    const unsigned short* __restrict__ fsoff, size_t fstride,
    float d0, float d1, float d2, float d3, float4 at) {
  float m = -1e30f, den = 0.f;
  float a0 = 0.f, a1 = 0.f, a2 = 0.f, a3 = 0.f;
  for (int e = e0; e < e1; ++e) {
    int s = csrc[e];
    ushort4 us = *(const ushort4*)(fsoff + (size_t)s * fstride);
    float f0 = bu2f(us.x), f1 = bu2f(us.y), f2 = bu2f(us.z), f3 = bu2f(us.w);
    float t0 = f0 + d0; t0 = t0 > 0.f ? t0 : 0.2f * t0;
    float t1 = f1 + d1; t1 = t1 > 0.f ? t1 : 0.2f * t1;
    float t2 = f2 + d2; t2 = t2 > 0.f ? t2 : 0.2f * t2;
    float t3 = f3 + d3; t3 = t3 > 0.f ? t3 : 0.2f * t3;
    float lg = t0 * at.x + t1 * at.y + t2 * at.z + t3 * at.w;
    lg += __shfl_xor(lg, 1);
    lg += __shfl_xor(lg, 2);
    lg += __shfl_xor(lg, 4);
    if (lg > m) {
      float c = __expf(m - lg);
      den *= c; a0 *= c; a1 *= c; a2 *= c; a3 *= c;
      m = lg;
    }
    float ex = __expf(lg - m);
    den += ex;
    a0 += ex * f0; a1 += ex * f1; a2 += ex * f2; a3 += ex * f3;
  }
  float inv = (den > 0.f) ? 1.f / den : 0.f;
  return make_float4(a0 * inv, a1 * inv, a2 * inv, a3 * inv);
}

// -------- tile nodes: road (F1) + tb (F2) fused, scale+ReLU epilogue --------
__global__ __launch_bounds__(256) void node_gat_tile(
    const int* __restrict__ offsA, const int* __restrict__ csA,
    const int* __restrict__ offsB, const int* __restrict__ csB,
    const bf16* __restrict__ F1, const bf16* __restrict__ F2,
    const float* __restrict__ attnL, float scale,
    bf16* __restrict__ hnew, float* __restrict__ outf) {
  int wave = blockIdx.x * 4 + (threadIdx.x >> 6);
  if (wave >= NT) return;
  int lane = threadIdx.x & 63;
  int off = (lane >> 3) * DD + (lane & 7) * 4;
  const unsigned short* F1u = (const unsigned short*)F1;
  const unsigned short* F2u = (const unsigned short*)F2;

  ushort4 udA = *(const ushort4*)(F1u + (size_t)wave * 1024 + 256 + off);
  float4 atA = *(const float4*)(attnL + off);
  float4 ra = gat_pass(offsA[wave], offsA[wave + 1], csA, F1u + off, 1024,
                       bu2f(udA.x), bu2f(udA.y), bu2f(udA.z), bu2f(udA.w), atA);

  ushort4 udB = *(const ushort4*)(F1u + (size_t)wave * 1024 + 512 + off);
  float4 atB = *(const float4*)(attnL + 256 + off);
  float4 rb = gat_pass(offsB[wave], offsB[wave + 1], csB, F2u + off, 512,
                       bu2f(udB.x), bu2f(udB.y), bu2f(udB.z), bu2f(udB.w), atB);

  float v0 = (ra.x + rb.x) * scale; v0 = v0 > 0.f ? v0 : 0.f;
  float v1 = (ra.y + rb.y) * scale; v1 = v1 > 0.f ? v1 : 0.f;
  float v2 = (ra.z + rb.z) * scale; v2 = v2 > 0.f ? v2 : 0.f;
  float v3 = (ra.w + rb.w) * scale; v3 = v3 > 0.f ? v3 : 0.f;

  size_t base = (size_t)wave * CC + off;
  *(ushort4*)((unsigned short*)hnew + base) =
      make_ushort4(f2bu(v0), f2bu(v1), f2bu(v2), f2bu(v3));
  if (outf) *(float4*)(outf + base) = make_float4(v0, v1, v2, v3);
}

// -------- poi nodes: ct relation --------
__global__ __launch_bounds__(256) void node_gat_poi(
    const int* __restrict__ offsC, const int* __restrict__ csC,
    const bf16* __restrict__ F1, const bf16* __restrict__ F2,
    const float* __restrict__ attnL,
    bf16* __restrict__ hnew, float* __restrict__ outf) {
  int wave = blockIdx.x * 4 + (threadIdx.x >> 6);
  if (wave >= NP) return;
  int lane = threadIdx.x & 63;
  int off = (lane >> 3) * DD + (lane & 7) * 4;
  const unsigned short* F1u = (const unsigned short*)F1;
  const unsigned short* F2u = (const unsigned short*)F2;

  ushort4 ud = *(const ushort4*)(F2u + (size_t)wave * 512 + 256 + off);
  float4 at = *(const float4*)(attnL + 512 + off);
  float4 r = gat_pass(offsC[wave], offsC[wave + 1], csC, F1u + 768 + off, 1024,
                      bu2f(ud.x), bu2f(ud.y), bu2f(ud.z), bu2f(ud.w), at);

  float v0 = r.x > 0.f ? r.x : 0.f;
  float v1 = r.y > 0.f ? r.y : 0.f;
  float v2 = r.z > 0.f ? r.z : 0.f;
  float v3 = r.w > 0.f ? r.w : 0.f;

  size_t base = (size_t)wave * CC + off;
  *(ushort4*)((unsigned short*)hnew + base) =
      make_ushort4(f2bu(v0), f2bu(v1), f2bu(v2), f2bu(v3));
  if (outf) *(float4*)(outf + base) = make_float4(v0, v1, v2, v3);
}

extern "C" void kernel_launch(void* const* d_in, const int* in_sizes, int n_in,
                              void* d_out, int out_size, void* d_ws, size_t ws_size,
                              hipStream_t stream) {
  const float* x_tile = (const float*)d_in[0];
  const float* x_poi  = (const float*)d_in[1];
  const int* src_road = (const int*)d_in[2];
  const int* dst_road = (const int*)d_in[3];
  const int* src_tb   = (const int*)d_in[4];
  const int* dst_tb   = (const int*)d_in[5];
  const int* src_ct   = (const int*)d_in[6];
  const int* dst_ct   = (const int*)d_in[7];
  const float* Wsrc[3] = {(const float*)d_in[8],  (const float*)d_in[13], (const float*)d_in[18]};
  const float* bsrc[3] = {(const float*)d_in[9],  (const float*)d_in[14], (const float*)d_in[19]};
  const float* Wdst[3] = {(const float*)d_in[10], (const float*)d_in[15], (const float*)d_in[20]};
  const float* bdst[3] = {(const float*)d_in[11], (const float*)d_in[16], (const float*)d_in[21]};
  const float* attn[3] = {(const float*)d_in[12], (const float*)d_in[17], (const float*)d_in[22]};

  // workspace (~262 MB): ht2/hp2 4x25.6 | F1 102.4 | F2 51.2 | CSR ~3.6 | W ~2
  bf16* hbuf = (bf16*)d_ws;
  bf16* ht2[2] = {hbuf, hbuf + (size_t)NT * CC};
  bf16* hp2[2] = {hbuf + 2 * (size_t)NT * CC, hbuf + 3 * (size_t)NT * CC};
  bf16* F1 = hbuf + 4 * (size_t)NT * CC;
  bf16* F2 = F1 + (size_t)NT * 1024;
  int* offs = (int*)(F2 + (size_t)NT * 512);
  int* deg  = offs + 3 * (NT + 1);
  int* csrc = deg + 3 * NT;
  int* bsum = csrc + (size_t)3 * NE;
  int* boff = bsum + 3 * NBLK;
  uintptr_t wp = ((uintptr_t)(boff + 3 * NBLK) + 63) & ~(uintptr_t)63;
  bf16* W1c[3], *W2c[3];
  {
    bf16* w = (bf16*)wp;
    for (int l = 0; l < 3; l++) {
      int K = (l == 0) ? 128 : 256;
      W1c[l] = w; w += (size_t)1024 * K;
      W2c[l] = w; w += (size_t)512 * K;
    }
    wp = (uintptr_t)w;
  }
  float* b1 = (float*)((wp + 63) & ~(uintptr_t)63);
  float* b2 = b1 + 3 * 1024;

  // input converts
  cvt_f2b<<<(NT * 128 + 255) / 256, 256, 0, stream>>>(x_tile, ht2[0], NT * 128);
  cvt_f2b<<<(NP * 128 + 255) / 256, 256, 0, stream>>>(x_poi, hp2[0], NP * 128);

  // weight + bias prep
  {
    WtArgs wa;
    BiArgs ba;
    for (int l = 0; l < 3; l++) {
      wa.Ws[l] = Wsrc[l]; wa.Wd[l] = Wdst[l];
      wa.W1[l] = W1c[l];  wa.W2[l] = W2c[l];
      ba.bs[l] = bsrc[l]; ba.bd[l] = bdst[l];
    }
    ba.b1 = b1; ba.b2 = b2;
    dim3 gw(256, 6, 3);
    wt_cvt_all<<<gw, 256, 0, stream>>>(wa);
    dim3 gb(6, 3);
    bias_cat<<<gb, 256, 0, stream>>>(ba);
  }

  // CSR build
  zero_i<<<(3 * NT + 255) / 256, 256, 0, stream>>>(deg, 3 * NT);
  {
    dim3 ge((NE + 255) / 256, 3);
    hist3<<<ge, 256, 0, stream>>>(dst_road, dst_tb, dst_ct, deg);
    dim3 gn(NBLK, 3);
    scan_s1<<<gn, 256, 0, stream>>>(deg, bsum);
    scan_s2<<<1, 256, 0, stream>>>(bsum, boff, offs);
    scan_s3<<<gn, 256, 0, stream>>>(deg, boff, offs, deg);
    fill3<<<ge, 256, 0, stream>>>(dst_road, dst_tb, dst_ct,
                                  src_road, src_tb, src_ct, deg, csrc);
  }

  int nbm = (NT + BM - 1) / BM;  // 391
  int cb = 0;
  for (int l = 0; l < 3; l++) {
    int K = (l == 0) ? 128 : 256;
    bf16* ht_c = ht2[cb], *hp_c = hp2[cb];
    bf16* ht_n = ht2[cb ^ 1], *hp_n = hp2[cb ^ 1];
    float st = (l == 1) ? 0.5f : 1.0f;
    float* outT = (l == 2) ? (float*)d_out : nullptr;
    float* outP = (l == 2) ? ((float*)d_out + (size_t)NT * CC) : nullptr;

    {
      int NW = 8 * nbm, q8 = NW / 8, r8 = NW % 8;
      gemm_mfma<<<NW, 256, 0, stream>>>(ht_c, W1c[l], b1 + l * 1024, F1,
                                        NT, K, 1024, 8, q8, r8);
    }
    {
      int NW = 4 * nbm, q8 = NW / 8, r8 = NW % 8;
      gemm_mfma<<<NW, 256, 0, stream>>>(hp_c, W2c[l], b2 + l * 512, F2,
                                        NT, K, 512, 4, q8, r8);
    }

    node_gat_tile<<<(NT + 3) / 4, 256, 0, stream>>>(
        offs, csrc, offs + (NT + 1), csrc + NE, F1, F2, attn[l], st, ht_n, outT);
    node_gat_poi<<<(NP + 3) / 4, 256, 0, stream>>>(
        offs + 2 * (NT + 1), csrc + 2 * (size_t)NE, F1, F2, attn[l], hp_n, outP);

    cb ^= 1;
  }
}

// Round 9
// 626.657 us; speedup vs baseline: 12.7790x; 1.1280x over previous
//
#include <hip/hip_runtime.h>
#include <hip/hip_bf16.h>

typedef __hip_bfloat16 bf16;

#define NT 50000
#define NP 50000
#define NE 200000
#define HH 8
#define DD 32
#define CC 256   // H*D
#define NBLK 196 // ceil(NT/256)

#define BM 128
#define BK 32

typedef short s8v __attribute__((ext_vector_type(8)));   // 8 bf16 (4 VGPRs)
typedef float f4v __attribute__((ext_vector_type(4)));   // 4 f32 acc

__device__ __forceinline__ float bu2f(unsigned short u) {
  return __uint_as_float(((unsigned)u) << 16);
}
__device__ __forceinline__ unsigned short f2bu(float x) {
  bf16 b = __float2bfloat16(x);
  return *(unsigned short*)&b;
}

__device__ __forceinline__ void gload_lds16(const void* g, void* l) {
  __builtin_amdgcn_global_load_lds(
      (const __attribute__((address_space(1))) void*)g,
      (__attribute__((address_space(3))) void*)l, 16, 0, 0);
}

// -------- input convert --------
__global__ __launch_bounds__(256) void cvt_f2b(const float* __restrict__ in,
                                               bf16* __restrict__ out, int n) {
  int i = blockIdx.x * 256 + threadIdx.x;
  if (i < n) out[i] = __float2bfloat16(in[i]);
}

// -------- weight prep --------
// W1cat[l] (1024 x K) rows: [Ws rel0 | Wd rel0 | Wd rel1 | Ws rel2]
// W2cat[l] ( 512 x K) rows: [Ws rel1 | Wd rel2]
struct WtArgs {
  const float* Ws[3]; const float* Wd[3];
  bf16* W1[3]; bf16* W2[3];
};
__global__ __launch_bounds__(256) void wt_cvt_all(WtArgs a) {
  int l = blockIdx.z, y = blockIdx.y;
  int K = (l == 0) ? 128 : 256;
  int idx = blockIdx.x * 256 + threadIdx.x;
  if (idx >= 256 * K) return;
  int n = idx / K, k = idx - n * K;
  const float* W; bf16* D; int dn;
  if (y == 0)      { W = a.Ws[l];                       D = a.W1[l]; dn = n; }
  else if (y == 1) { W = a.Wd[l];                       D = a.W1[l]; dn = n + 256; }
  else if (y == 2) { W = a.Wd[l] + (size_t)1 * K * 256; D = a.W1[l]; dn = n + 512; }
  else if (y == 3) { W = a.Ws[l] + (size_t)2 * K * 256; D = a.W1[l]; dn = n + 768; }
  else if (y == 4) { W = a.Ws[l] + (size_t)1 * K * 256; D = a.W2[l]; dn = n; }
  else             { W = a.Wd[l] + (size_t)2 * K * 256; D = a.W2[l]; dn = n + 256; }
  D[(size_t)dn * K + k] = __float2bfloat16(W[(size_t)k * 256 + n]);
}

struct BiArgs {
  const float* bs[3]; const float* bd[3];
  float* b1; float* b2;  // b1: 3*1024, b2: 3*512
};
__global__ __launch_bounds__(256) void bias_cat(BiArgs a) {
  int l = blockIdx.y, y = blockIdx.x;
  int n = threadIdx.x;
  float v;
  if (y == 0)      v = a.bs[l][n];
  else if (y == 1) v = a.bd[l][n];
  else if (y == 2) v = a.bd[l][256 + n];
  else if (y == 3) v = a.bs[l][512 + n];
  else if (y == 4) v = a.bs[l][256 + n];
  else             v = a.bd[l][512 + n];
  if (y < 4) a.b1[l * 1024 + y * 256 + n] = v;
  else       a.b2[l * 512 + (y - 4) * 256 + n] = v;
}

__global__ __launch_bounds__(256) void zero_i(int* __restrict__ p, int n) {
  int i = blockIdx.x * 256 + threadIdx.x;
  if (i < n) p[i] = 0;
}

// -------- CSR build (batched over 3 relations via blockIdx.y) --------
__global__ __launch_bounds__(256) void hist3(
    const int* __restrict__ d0, const int* __restrict__ d1,
    const int* __restrict__ d2, int* __restrict__ deg) {
  int r = blockIdx.y;
  int e = blockIdx.x * 256 + threadIdx.x;
  if (e >= NE) return;
  const int* d = (r == 0) ? d0 : (r == 1) ? d1 : d2;
  atomicAdd(&deg[r * NT + d[e]], 1);
}

__global__ __launch_bounds__(256) void scan_s1(const int* __restrict__ deg,
                                               int* __restrict__ bsum) {
  __shared__ int buf[256];
  int r = blockIdx.y, b = blockIdx.x, t = threadIdx.x;
  int idx = b * 256 + t;
  buf[t] = (idx < NT) ? deg[r * NT + idx] : 0;
  __syncthreads();
  for (int s = 128; s > 0; s >>= 1) {
    if (t < s) buf[t] += buf[t + s];
    __syncthreads();
  }
  if (t == 0) bsum[r * NBLK + b] = buf[0];
}

__global__ __launch_bounds__(256) void scan_s2(
    const int* __restrict__ bsum, int* __restrict__ boff,
    int* __restrict__ offs) {
  __shared__ int buf[256];
  int t = threadIdx.x;
  for (int r = 0; r < 3; r++) {
    int v = (t < NBLK) ? bsum[r * NBLK + t] : 0;
    buf[t] = v;
    __syncthreads();
    for (int s = 1; s < 256; s <<= 1) {
      int u = (t >= s) ? buf[t - s] : 0;
      __syncthreads();
      buf[t] += u;
      __syncthreads();
    }
    if (t < NBLK) boff[r * NBLK + t] = buf[t] - v;
    if (t == 255) offs[(size_t)r * (NT + 1) + NT] = buf[255];
    __syncthreads();
  }
}

__global__ __launch_bounds__(256) void scan_s3(
    const int* __restrict__ deg, const int* __restrict__ boff,
    int* __restrict__ offs, int* __restrict__ cursor) {
  __shared__ int buf[256];
  int r = blockIdx.y, b = blockIdx.x, t = threadIdx.x;
  int idx = b * 256 + t;
  int v = (idx < NT) ? deg[r * NT + idx] : 0;
  buf[t] = v;
  __syncthreads();
  for (int s = 1; s < 256; s <<= 1) {
    int u = (t >= s) ? buf[t - s] : 0;
    __syncthreads();
    buf[t] += u;
    __syncthreads();
  }
  int o = boff[r * NBLK + b] + buf[t] - v;
  if (idx < NT) {
    offs[(size_t)r * (NT + 1) + idx] = o;
    cursor[r * NT + idx] = o;
  }
}

__global__ __launch_bounds__(256) void fill3(
    const int* __restrict__ d0, const int* __restrict__ d1,
    const int* __restrict__ d2, const int* __restrict__ s0,
    const int* __restrict__ s1, const int* __restrict__ s2,
    int* __restrict__ cursor, int* __restrict__ csrc) {
  int r = blockIdx.y;
  int e = blockIdx.x * 256 + threadIdx.x;
  if (e >= NE) return;
  const int* d = (r == 0) ? d0 : (r == 1) ? d1 : d2;
  const int* s = (r == 0) ? s0 : (r == 1) ? s1 : s2;
  int p = atomicAdd(&cursor[r * NT + d[e]], 1);
  csrc[(size_t)r * NE + p] = s[e];
}

// -------- dual MFMA GEMM: C1 = A1*B1t^T + b1 (Nc1), C2 = A2*B2t^T + b2 ------
// XCD-chunked bijective 1D grid remap over combined block range.
// LDS staging slot s holds (row s>>2, k-chunk (s&3)^((s>>3)&3)).
// Epilogue repacks C through LDS ((row&7) chunk-XOR) -> 16B coalesced stores.
__global__ __launch_bounds__(256) void gemm_dual(
    const bf16* __restrict__ A1, const bf16* __restrict__ B1t,
    const float* __restrict__ bias1, bf16* __restrict__ C1, int Nc1,
    const bf16* __restrict__ A2, const bf16* __restrict__ B2t,
    const float* __restrict__ bias2, bf16* __restrict__ C2, int Nc2,
    int M, int K, int NW1, int q8, int r8) {
  __shared__ short LDS[16384];   // A bufs [0,8192), B bufs [8192,16384); C tile overlays all
  int bid = blockIdx.x;
  int xcd = bid & 7, pos = bid >> 3;
  int wg = (xcd < r8 ? xcd * (q8 + 1) : r8 * (q8 + 1) + (xcd - r8) * q8) + pos;

  const bf16* A; const bf16* Bt; const float* bias; bf16* Cout; int Ncols;
  if (wg < NW1) { A = A1; Bt = B1t; bias = bias1; Cout = C1; Ncols = Nc1; }
  else { wg -= NW1; A = A2; Bt = B2t; bias = bias2; Cout = C2; Ncols = Nc2; }
  int nbn = Ncols >> 7;
  int bm = wg / nbn, bn = wg - bm * nbn;

  int t = threadIdx.x;
  int lane = t & 63;
  int wid = t >> 6;
  int wm = wid >> 1, wn = wid & 1;
  int row0 = bm * BM, col0 = bn * BM;

  f4v acc[4][4] = {};

  const bf16* Abase = A + (size_t)row0 * K;
  const bf16* Bbase = Bt + (size_t)col0 * K;
  int wbase = (t & ~63);

  auto stage = [&](int buf, int ks) {
    int kofs = ks * BK;
    #pragma unroll
    for (int j = 0; j < 2; j++) {
      int slot = j * 256 + t;
      int r = slot >> 2;
      int c = (slot & 3) ^ ((slot >> 3) & 3);   // inverse swizzle on source
      gload_lds16(Abase + (size_t)r * K + kofs + c * 8,
                  &LDS[buf * 4096 + (j * 256 + wbase) * 8]);
    }
    #pragma unroll
    for (int j = 0; j < 2; j++) {
      int slot = j * 256 + t;
      int r = slot >> 2;
      int c = (slot & 3) ^ ((slot >> 3) & 3);
      gload_lds16(Bbase + (size_t)r * K + kofs + c * 8,
                  &LDS[8192 + buf * 4096 + (j * 256 + wbase) * 8]);
    }
  };

  int nk = K / BK;
  int cur = 0;
  stage(0, 0);
  __syncthreads();

  for (int ks = 0; ks < nk; ks++) {
    if (ks + 1 < nk) stage(cur ^ 1, ks + 1);
    int c = lane >> 4;
    int rr = lane & 15;
    s8v af[4], bfv[4];
    #pragma unroll
    for (int mi = 0; mi < 4; mi++) {
      int R = wm * 64 + mi * 16 + rr;
      af[mi] = *(const s8v*)&LDS[cur * 4096 + (R * 4 + (c ^ ((R >> 1) & 3))) * 8];
    }
    #pragma unroll
    for (int ni = 0; ni < 4; ni++) {
      int R = wn * 64 + ni * 16 + rr;
      bfv[ni] = *(const s8v*)&LDS[8192 + cur * 4096 + (R * 4 + (c ^ ((R >> 1) & 3))) * 8];
    }
    #pragma unroll
    for (int mi = 0; mi < 4; mi++)
      #pragma unroll
      for (int ni = 0; ni < 4; ni++)
        acc[mi][ni] = __builtin_amdgcn_mfma_f32_16x16x32_bf16(
            af[mi], bfv[ni], acc[mi][ni], 0, 0, 0);
    __syncthreads();
    cur ^= 1;
  }

  // ---- epilogue: bias + bf16 pack into LDS C tile [128][128] (chunk-XOR) ----
  #pragma unroll
  for (int mi = 0; mi < 4; mi++) {
    #pragma unroll
    for (int ni = 0; ni < 4; ni++) {
      int colL = wn * 64 + ni * 16 + (lane & 15);
      float bv = bias[col0 + colL];
      #pragma unroll
      for (int r = 0; r < 4; r++) {
        int rowL = wm * 64 + mi * 16 + (lane >> 4) * 4 + r;
        int chunk = (colL >> 3) ^ (rowL & 7);
        LDS[rowL * 128 + chunk * 8 + (colL & 7)] = f2bu(acc[mi][ni][r] + bv);
      }
    }
  }
  __syncthreads();
  // ---- coalesced store: thread -> (row t>>1, 64-col half t&1) ----
  {
    int rowL = t >> 1, hf = t & 1;
    int grow = row0 + rowL;
    if (grow < M) {
      unsigned short* Cu = (unsigned short*)Cout;
      #pragma unroll
      for (int j = 0; j < 8; j++) {
        int chunkL = hf * 8 + j;
        s8v v = *(const s8v*)&LDS[rowL * 128 + (chunkL ^ (rowL & 7)) * 8];
        *(s8v*)&Cu[(size_t)grow * Ncols + col0 + chunkL * 8] = v;
      }
    }
  }
}

// -------- edge logit helper --------
__device__ __forceinline__ float edge_logit(
    ushort4 u, float d0, float d1, float d2, float d3, float4 at,
    float& f0, float& f1, float& f2, float& f3) {
  f0 = bu2f(u.x); f1 = bu2f(u.y); f2 = bu2f(u.z); f3 = bu2f(u.w);
  float t0 = f0 + d0; t0 = t0 > 0.f ? t0 : 0.2f * t0;
  float t1 = f1 + d1; t1 = t1 > 0.f ? t1 : 0.2f * t1;
  float t2 = f2 + d2; t2 = t2 > 0.f ? t2 : 0.2f * t2;
  float t3 = f3 + d3; t3 = t3 > 0.f ? t3 : 0.2f * t3;
  float lg = t0 * at.x + t1 * at.y + t2 * at.z + t3 * at.w;
  lg += __shfl_xor(lg, 1);
  lg += __shfl_xor(lg, 2);
  lg += __shfl_xor(lg, 4);
  return lg;
}

// -------- branchless online-softmax gather, 2-edge unrolled --------
__device__ __forceinline__ float4 gat_pass(
    int e0, int e1, const int* __restrict__ csrc,
    const unsigned short* __restrict__ base, size_t stride,
    float d0, float d1, float d2, float d3, float4 at) {
  float m = -1e30f, den = 0.f;
  float a0 = 0.f, a1 = 0.f, a2 = 0.f, a3 = 0.f;
  int e = e0;
  for (; e + 2 <= e1; e += 2) {
    int s0 = csrc[e], s1 = csrc[e + 1];
    ushort4 u0 = *(const ushort4*)(base + (size_t)s0 * stride);
    ushort4 u1 = *(const ushort4*)(base + (size_t)s1 * stride);
    float f0, f1, f2, f3, g0, g1, g2, g3;
    float lg0 = edge_logit(u0, d0, d1, d2, d3, at, f0, f1, f2, f3);
    float lg1 = edge_logit(u1, d0, d1, d2, d3, at, g0, g1, g2, g3);
    float mn = fmaxf(m, fmaxf(lg0, lg1));
    float c = __expf(m - mn);
    float x0 = __expf(lg0 - mn);
    float x1 = __expf(lg1 - mn);
    den = den * c + x0 + x1;
    a0 = a0 * c + x0 * f0 + x1 * g0;
    a1 = a1 * c + x0 * f1 + x1 * g1;
    a2 = a2 * c + x0 * f2 + x1 * g2;
    a3 = a3 * c + x0 * f3 + x1 * g3;
    m = mn;
  }
  if (e < e1) {
    int s0 = csrc[e];
    ushort4 u0 = *(const ushort4*)(base + (size_t)s0 * stride);
    float f0, f1, f2, f3;
    float lg0 = edge_logit(u0, d0, d1, d2, d3, at, f0, f1, f2, f3);
    float mn = fmaxf(m, lg0);
    float c = __expf(m - mn);
    float x0 = __expf(lg0 - mn);
    den = den * c + x0;
    a0 = a0 * c + x0 * f0;
    a1 = a1 * c + x0 * f1;
    a2 = a2 * c + x0 * f2;
    a3 = a3 * c + x0 * f3;
  }
  float inv = (den > 0.f) ? 1.f / den : 0.f;
  return make_float4(a0 * inv, a1 * inv, a2 * inv, a3 * inv);
}

// -------- merged node kernel: tile (road+tb) waves then poi (ct) waves ------
__global__ __launch_bounds__(256) void node_gat_all(
    const int* __restrict__ offs, const int* __restrict__ csrc,
    const bf16* __restrict__ F1, const bf16* __restrict__ F2,
    const float* __restrict__ attnL, float scale,
    bf16* __restrict__ ht_n, bf16* __restrict__ hp_n,
    float* __restrict__ outT, float* __restrict__ outP) {
  int gw = blockIdx.x * 4 + (threadIdx.x >> 6);
  int lane = threadIdx.x & 63;
  int off = (lane >> 3) * DD + (lane & 7) * 4;
  const unsigned short* F1u = (const unsigned short*)F1;
  const unsigned short* F2u = (const unsigned short*)F2;

  if (gw < NT) {
    // tile: road (fs in F1 blk0, fd F1 blk1) + tb (fs in F2 blk0, fd F1 blk2)
    ushort4 udA = *(const ushort4*)(F1u + (size_t)gw * 1024 + 256 + off);
    float4 atA = *(const float4*)(attnL + off);
    float4 ra = gat_pass(offs[gw], offs[gw + 1], csrc, F1u + off, 1024,
                         bu2f(udA.x), bu2f(udA.y), bu2f(udA.z), bu2f(udA.w), atA);

    const int* offsB = offs + (NT + 1);
    ushort4 udB = *(const ushort4*)(F1u + (size_t)gw * 1024 + 512 + off);
    float4 atB = *(const float4*)(attnL + 256 + off);
    float4 rb = gat_pass(offsB[gw], offsB[gw + 1], csrc + NE, F2u + off, 512,
                         bu2f(udB.x), bu2f(udB.y), bu2f(udB.z), bu2f(udB.w), atB);

    float v0 = (ra.x + rb.x) * scale; v0 = v0 > 0.f ? v0 : 0.f;
    float v1 = (ra.y + rb.y) * scale; v1 = v1 > 0.f ? v1 : 0.f;
    float v2 = (ra.z + rb.z) * scale; v2 = v2 > 0.f ? v2 : 0.f;
    float v3 = (ra.w + rb.w) * scale; v3 = v3 > 0.f ? v3 : 0.f;

    size_t base = (size_t)gw * CC + off;
    *(ushort4*)((unsigned short*)ht_n + base) =
        make_ushort4(f2bu(v0), f2bu(v1), f2bu(v2), f2bu(v3));
    if (outT) *(float4*)(outT + base) = make_float4(v0, v1, v2, v3);
  } else {
    int w = gw - NT;
    // poi: ct (fs in F1 blk3, fd F2 blk1)
    const int* offsC = offs + 2 * (NT + 1);
    ushort4 ud = *(const ushort4*)(F2u + (size_t)w * 512 + 256 + off);
    float4 at = *(const float4*)(attnL + 512 + off);
    float4 r = gat_pass(offsC[w], offsC[w + 1], csrc + 2 * (size_t)NE,
                        F1u + 768 + off, 1024,
                        bu2f(ud.x), bu2f(ud.y), bu2f(ud.z), bu2f(ud.w), at);

    float v0 = r.x > 0.f ? r.x : 0.f;
    float v1 = r.y > 0.f ? r.y : 0.f;
    float v2 = r.z > 0.f ? r.z : 0.f;
    float v3 = r.w > 0.f ? r.w : 0.f;

    size_t base = (size_t)w * CC + off;
    *(ushort4*)((unsigned short*)hp_n + base) =
        make_ushort4(f2bu(v0), f2bu(v1), f2bu(v2), f2bu(v3));
    if (outP) *(float4*)(outP + base) = make_float4(v0, v1, v2, v3);
  }
}

extern "C" void kernel_launch(void* const* d_in, const int* in_sizes, int n_in,
                              void* d_out, int out_size, void* d_ws, size_t ws_size,
                              hipStream_t stream) {
  const float* x_tile = (const float*)d_in[0];
  const float* x_poi  = (const float*)d_in[1];
  const int* src_road = (const int*)d_in[2];
  const int* dst_road = (const int*)d_in[3];
  const int* src_tb   = (const int*)d_in[4];
  const int* dst_tb   = (const int*)d_in[5];
  const int* src_ct   = (const int*)d_in[6];
  const int* dst_ct   = (const int*)d_in[7];
  const float* Wsrc[3] = {(const float*)d_in[8],  (const float*)d_in[13], (const float*)d_in[18]};
  const float* bsrc[3] = {(const float*)d_in[9],  (const float*)d_in[14], (const float*)d_in[19]};
  const float* Wdst[3] = {(const float*)d_in[10], (const float*)d_in[15], (const float*)d_in[20]};
  const float* bdst[3] = {(const float*)d_in[11], (const float*)d_in[16], (const float*)d_in[21]};
  const float* attn[3] = {(const float*)d_in[12], (const float*)d_in[17], (const float*)d_in[22]};

  // workspace (~262 MB): ht2/hp2 4x25.6 | F1 102.4 | F2 51.2 | CSR ~3.6 | W ~2
  bf16* hbuf = (bf16*)d_ws;
  bf16* ht2[2] = {hbuf, hbuf + (size_t)NT * CC};
  bf16* hp2[2] = {hbuf + 2 * (size_t)NT * CC, hbuf + 3 * (size_t)NT * CC};
  bf16* F1 = hbuf + 4 * (size_t)NT * CC;
  bf16* F2 = F1 + (size_t)NT * 1024;
  int* offs = (int*)(F2 + (size_t)NT * 512);
  int* deg  = offs + 3 * (NT + 1);
  int* csrc = deg + 3 * NT;
  int* bsum = csrc + (size_t)3 * NE;
  int* boff = bsum + 3 * NBLK;
  uintptr_t wp = ((uintptr_t)(boff + 3 * NBLK) + 63) & ~(uintptr_t)63;
  bf16* W1c[3], *W2c[3];
  {
    bf16* w = (bf16*)wp;
    for (int l = 0; l < 3; l++) {
      int K = (l == 0) ? 128 : 256;
      W1c[l] = w; w += (size_t)1024 * K;
      W2c[l] = w; w += (size_t)512 * K;
    }
    wp = (uintptr_t)w;
  }
  float* b1 = (float*)((wp + 63) & ~(uintptr_t)63);
  float* b2 = b1 + 3 * 1024;

  // input converts
  cvt_f2b<<<(NT * 128 + 255) / 256, 256, 0, stream>>>(x_tile, ht2[0], NT * 128);
  cvt_f2b<<<(NP * 128 + 255) / 256, 256, 0, stream>>>(x_poi, hp2[0], NP * 128);

  // weight + bias prep
  {
    WtArgs wa;
    BiArgs ba;
    for (int l = 0; l < 3; l++) {
      wa.Ws[l] = Wsrc[l]; wa.Wd[l] = Wdst[l];
      wa.W1[l] = W1c[l];  wa.W2[l] = W2c[l];
      ba.bs[l] = bsrc[l]; ba.bd[l] = bdst[l];
    }
    ba.b1 = b1; ba.b2 = b2;
    dim3 gw(256, 6, 3);
    wt_cvt_all<<<gw, 256, 0, stream>>>(wa);
    dim3 gb(6, 3);
    bias_cat<<<gb, 256, 0, stream>>>(ba);
  }

  // CSR build
  zero_i<<<(3 * NT + 255) / 256, 256, 0, stream>>>(deg, 3 * NT);
  {
    dim3 ge((NE + 255) / 256, 3);
    hist3<<<ge, 256, 0, stream>>>(dst_road, dst_tb, dst_ct, deg);
    dim3 gn(NBLK, 3);
    scan_s1<<<gn, 256, 0, stream>>>(deg, bsum);
    scan_s2<<<1, 256, 0, stream>>>(bsum, boff, offs);
    scan_s3<<<gn, 256, 0, stream>>>(deg, boff, offs, deg);
    fill3<<<ge, 256, 0, stream>>>(dst_road, dst_tb, dst_ct,
                                  src_road, src_tb, src_ct, deg, csrc);
  }

  int nbm = (NT + BM - 1) / BM;  // 391
  int cb = 0;
  for (int l = 0; l < 3; l++) {
    int K = (l == 0) ? 128 : 256;
    bf16* ht_c = ht2[cb], *hp_c = hp2[cb];
    bf16* ht_n = ht2[cb ^ 1], *hp_n = hp2[cb ^ 1];
    float st = (l == 1) ? 0.5f : 1.0f;
    float* outT = (l == 2) ? (float*)d_out : nullptr;
    float* outP = (l == 2) ? ((float*)d_out + (size_t)NT * CC) : nullptr;

    int NW1 = 8 * nbm, NW2 = 4 * nbm;
    int NW = NW1 + NW2, q8 = NW / 8, r8 = NW % 8;
    gemm_dual<<<NW, 256, 0, stream>>>(
        ht_c, W1c[l], b1 + l * 1024, F1, 1024,
        hp_c, W2c[l], b2 + l * 512,  F2, 512,
        NT, K, NW1, q8, r8);

    node_gat_all<<<(NT + NP) / 4, 256, 0, stream>>>(
        offs, csrc, F1, F2, attn[l], st, ht_n, hp_n, outT, outP);

    cb ^= 1;
  }
}